// Round 13
// baseline (7617.936 us; speedup 1.0000x reference)
//
#include <hip/hip_runtime.h>
#include <hip/hip_bf16.h>
#include <hip/hip_cooperative_groups.h>
#include <cmath>

namespace cg = cooperative_groups;

typedef unsigned short u16;
typedef __attribute__((ext_vector_type(8))) short short8;
typedef __attribute__((ext_vector_type(4))) float floatx4;

#define DEVI __device__ __forceinline__

constexpr int cV = 32000, cE = 512, cT = 64, cH = 1024, cZ = 128, cB = 64, cPAD = 31999, cTP1 = 65;
constexpr long long LOGP_SZ = 133120000LL;   // B*(T+1)*V f32 elems
constexpr long long AMAT_OFF = 130990080LL;  // logp tail: 260 frag-rows x 32 x 512 u16
constexpr long long WBOUT_OFF = 38400000LL;  // logp rows [1200,1712): frag bf16 out_W
constexpr int SKIP_LO = 1200, SKIP_HI = 1712;  // 512 rows exactly

DEVI float b2f(u16 u) { return __uint_as_float(((unsigned)u) << 16); }
DEVI u16 f2b(float f) {
  unsigned u = __float_as_uint(f);
  unsigned r = u + 0x7FFFu + ((u >> 16) & 1u);
  return (u16)(r >> 16);
}
DEVI unsigned pk2(float lo, float hi) {
  __hip_bfloat162 t = __float22bfloat162_rn(make_float2(lo, hi));
  return *reinterpret_cast<unsigned*>(&t);
}
DEVI float sigm(float x) { return 1.f / (1.f + expf(-x)); }

DEVI short8 ldfragW(const float* __restrict__ p) {
  float4 x = *(const float4*)p, y = *(const float4*)(p + 4);
  union { unsigned u[4]; short8 s; } r;
  r.u[0] = pk2(x.x, x.y); r.u[1] = pk2(x.z, x.w);
  r.u[2] = pk2(y.x, y.y); r.u[3] = pk2(y.z, y.w);
  return r.s;
}

template <typename T>
DEVI short8 ldfrag(const T* __restrict__ p) {
  if constexpr (sizeof(T) == 2) return *(const short8*)(p);
  else return ldfragW((const float*)p);
}

template <int MAP>
DEVI int rmap(int r) {
  if constexpr (MAP == 1) return ((r & 3) << 10) | (r >> 2);  // n' -> g*1024+j
  else if constexpr (MAP == 2) return r & 63;                 // (t,b) row -> b
  else return r;
}

DEVI float dot_wf(const float* __restrict__ w, const float* __restrict__ s, int K) {
  float a0 = 0.f, a1 = 0.f, a2 = 0.f, a3 = 0.f;
#pragma unroll 4
  for (int k = 0; k < K; k += 8) {
    float4 p = *(const float4*)(w + k);
    float4 q = *(const float4*)(w + k + 4);
    a0 = fmaf(s[k + 0], p.x, a0); a1 = fmaf(s[k + 1], p.y, a1);
    a2 = fmaf(s[k + 2], p.z, a2); a3 = fmaf(s[k + 3], p.w, a3);
    a0 = fmaf(s[k + 4], q.x, a0); a1 = fmaf(s[k + 5], q.y, a1);
    a2 = fmaf(s[k + 6], q.z, a2); a3 = fmaf(s[k + 7], q.w, a3);
  }
  return (a0 + a1) + (a2 + a3);
}

__global__ __launch_bounds__(256) void k_zero(float* p, int n) {
  int i = blockIdx.x * 256 + threadIdx.x;
  if (i < n) p[i] = 0.f;
}

// ---------- generic MFMA GEMM: C[M,N] (+bias +D +C) = A[M,K] x B[N,K]^T ----------
template <typename AT, typename BT, typename CT, int AMAP, int BMAP, bool ADDC>
__global__ __launch_bounds__(64) void k_gemm(
    const AT* __restrict__ A, int lda, const BT* __restrict__ B, int ldb,
    const float* __restrict__ bias, const float* __restrict__ Dm, int ldd,
    CT* __restrict__ C, int ldc, int K) {
  int nblk = blockIdx.x, mblk = blockIdx.y;
  int lane = threadIdx.x;
  int lr = lane & 15, kg = lane >> 4;
  const BT* Bp = B + (size_t)rmap<BMAP>(nblk * 16 + lr) * ldb + kg * 8;
  const AT* Ap[4];
#pragma unroll
  for (int mf = 0; mf < 4; mf++)
    Ap[mf] = A + (size_t)rmap<AMAP>(mblk * 64 + mf * 16 + lr) * lda + kg * 8;
  floatx4 acc[4];
#pragma unroll
  for (int mf = 0; mf < 4; mf++) acc[mf] = (floatx4){0.f, 0.f, 0.f, 0.f};
#pragma unroll 4
  for (int ks = 0; ks < K / 32; ks++) {
    short8 bv = ldfrag(Bp + ks * 32);
#pragma unroll
    for (int mf = 0; mf < 4; mf++) {
      short8 av = ldfrag(Ap[mf] + ks * 32);
      acc[mf] = __builtin_amdgcn_mfma_f32_16x16x32_bf16(av, bv, acc[mf], 0, 0, 0);
    }
  }
  int n = nblk * 16 + lr;
  float bs = bias ? bias[n] : 0.f;
#pragma unroll
  for (int mf = 0; mf < 4; mf++) {
#pragma unroll
    for (int jj = 0; jj < 4; jj++) {
      int m = mblk * 64 + mf * 16 + kg * 4 + jj;
      size_t ci = (size_t)m * ldc + n;
      float v = acc[mf][jj] + bs;
      if (Dm) v += Dm[(size_t)rmap<AMAP>(m) * ldd + n];
      if constexpr (ADDC) {
        if constexpr (sizeof(CT) == 2) v += b2f(C[ci]);
        else v += C[ci];
      }
      if constexpr (sizeof(CT) == 2) C[ci] = f2b(v);
      else C[ci] = v;
    }
  }
}

// ---------- cooperative serial LSTM: all steps in one kernel, W panel in LDS ----------
// grid 256 x 64 thr. Block nb owns gate cols n' in [nb*16, nb*16+16) => j in [nb*4, nb*4+4).
// c state lives in registers (block-private). grid.sync() between steps.
template <int NSTEPS, bool DEC>
__global__ __launch_bounds__(64) void k_cells_all(
    const u16* __restrict__ G,    // [NSTEPS][64][4096] gates precomputed (bias folded)
    const u16* __restrict__ H0,   // initial h row-major [64][1024] (zeros) — encoder only
    const u16* __restrict__ Wb,   // row-major [4096][1024], n'-permuted rows
    u16* __restrict__ Hist,       // enc: encO [64b][64t][1024]; dec: Hh [66][64][1024]
    u16* __restrict__ Afrag) {    // dec only: frag-linear A
  cg::grid_group grid = cg::this_grid();
  int nb = blockIdx.x;
  int lane = threadIdx.x;
  int lr = lane & 15, kg = lane >> 4;
  __shared__ u16 wpan[16384];     // 32 KB: [ks(32)][512] frag-arranged W panel
  __shared__ float ldsT[16][65];
  {
    const u16* src = Wb + (size_t)(nb * 16 + lr) * cH + kg * 8;
#pragma unroll 4
    for (int ks = 0; ks < 32; ks++)
      *(short8*)(wpan + ks * 512 + lane * 8) = *(const short8*)(src + ks * 32);
  }
  float creg[4] = {0.f, 0.f, 0.f, 0.f};
  __syncthreads();
  for (int t = 0; t < NSTEPS; t++) {
    const u16* H;
    int strideH;
    if constexpr (DEC) {
      H = Hist + (size_t)t * cB * cH; strideH = cH;
    } else {
      H = t ? (Hist + (size_t)(t - 1) * cH) : H0;
      strideH = t ? (cT * cH) : cH;
    }
    floatx4 acc[4];
#pragma unroll
    for (int mf = 0; mf < 4; mf++) acc[mf] = (floatx4){0.f, 0.f, 0.f, 0.f};
#pragma unroll 8
    for (int ks = 0; ks < 32; ks++) {
      short8 bv = *(const short8*)(wpan + ks * 512 + lane * 8);
#pragma unroll
      for (int mf = 0; mf < 4; mf++) {
        short8 av = *(const short8*)(H + (size_t)(mf * 16 + lr) * strideH + ks * 32 + kg * 8);
        acc[mf] = __builtin_amdgcn_mfma_f32_16x16x32_bf16(av, bv, acc[mf], 0, 0, 0);
      }
    }
#pragma unroll
    for (int mf = 0; mf < 4; mf++)
#pragma unroll
      for (int jj = 0; jj < 4; jj++)
        ldsT[lr][mf * 16 + kg * 4 + jj] = acc[mf][jj];
    __syncthreads();  // single wave: cheap
    int b = lane;
    const u16* gp = G + ((size_t)t * cB + b) * 4096 + nb * 16;
    u16 hb[4];
#pragma unroll
    for (int a = 0; a < 4; a++) {
      ushort4 gv = *(const ushort4*)(gp + 4 * a);
      float gi = ldsT[4 * a + 0][b] + b2f(gv.x);
      float gf = ldsT[4 * a + 1][b] + b2f(gv.y);
      float gg = ldsT[4 * a + 2][b] + b2f(gv.z);
      float go = ldsT[4 * a + 3][b] + b2f(gv.w);
      float cc = creg[a];
      cc = sigm(gf) * cc + sigm(gi) * tanhf(gg);
      float hh = sigm(go) * tanhf(cc);
      creg[a] = cc;
      hb[a] = f2b(hh);
    }
    ushort4 hv = {hb[0], hb[1], hb[2], hb[3]};
    int j0 = nb * 4;
    if constexpr (DEC) {
      *(ushort4*)(Hist + ((size_t)(t + 1) * cB + b) * cH + j0) = hv;
      int m = b * cTP1 + t;
      size_t aidx = ((size_t)(m >> 4) * 32 + (j0 >> 5)) * 512 +
                    (size_t)((((j0 >> 3) & 3) * 16 + (m & 15)) * 8 + (j0 & 7));
      *(ushort4*)(Afrag + aidx) = hv;
    } else {
      *(ushort4*)(Hist + (size_t)b * (cT * cH) + (size_t)t * cH + j0) = hv;
    }
    __syncthreads();  // ldsT reuse guard
    grid.sync();
  }
}

// ---------- small prep kernels ----------
__global__ __launch_bounds__(256) void k_tr(const float* __restrict__ src, int ld,
                                            int R, float* __restrict__ dst) {
  __shared__ float tile[32][33];
  int c0 = blockIdx.x * 32, r0 = blockIdx.y * 32;
  int tx = threadIdx.x & 31, ty = threadIdx.x >> 5;
  for (int i = ty; i < 32; i += 8) tile[i][tx] = src[(size_t)(r0 + i) * ld + c0 + tx];
  __syncthreads();
  for (int i = ty; i < 32; i += 8) dst[(size_t)(c0 + i) * R + r0 + tx] = tile[tx][i];
}

__global__ __launch_bounds__(256) void k_gemv(const float* __restrict__ W, int ld,
                                              const float* __restrict__ x,
                                              const float* __restrict__ b,
                                              float* __restrict__ out, int K, int add) {
  int n = blockIdx.x * 256 + threadIdx.x;
  const float* w = W + (size_t)n * ld;
  float s = b ? b[n] : 0.f;
  for (int k = 0; k < K; k += 4) {
    float4 wv = *(const float4*)(w + k);
    float4 xv = *(const float4*)(x + k);
    s += wv.x * xv.x + wv.y * xv.y + wv.z * xv.z + wv.w * xv.w;
  }
  if (add) out[n] += s; else out[n] = s;
}

__global__ __launch_bounds__(256) void k_biasD(const float* __restrict__ bih,
                                               const float* __restrict__ bhh,
                                               const float* __restrict__ Wih,
                                               const float* __restrict__ u0,
                                               float* __restrict__ biasD) {
  int np = blockIdx.x * 256 + threadIdx.x;
  int src = ((np & 3) << 10) | (np >> 2);
  const float* w = Wih + (size_t)src * cH;
  float s = bih[src] + bhh[src];
  for (int k = 0; k < cH; k += 4) {
    float4 wv = *(const float4*)(w + k);
    float4 xv = *(const float4*)(u0 + k);
    s += wv.x * xv.x + wv.y * xv.y + wv.z * xv.z + wv.w * xv.w;
  }
  biasD[np] = s;
}

__global__ __launch_bounds__(256) void k_biasE(const float* __restrict__ bih,
                                               const float* __restrict__ bhh,
                                               float* __restrict__ biasE) {
  int np = blockIdx.x * 256 + threadIdx.x;
  int src = ((np & 3) << 10) | (np >> 2);
  biasE[np] = bih[src] + bhh[src];
}

__global__ __launch_bounds__(256) void k_permW(const float* __restrict__ Whh,
                                               u16* __restrict__ Wp) {
  int np = blockIdx.x;
  int src = ((np & 3) << 10) | (np >> 2);
  const float* w = Whh + (size_t)src * cH;
  u16* d = Wp + (size_t)np * cH;
  int tid = threadIdx.x;
#pragma unroll
  for (int p = 0; p < 4; p++) d[tid + p * 256] = f2b(w[tid + p * 256]);
}

// out_W (f32 row-major [32000][1024]) -> frag-linear bf16
__global__ __launch_bounds__(256) void k_cvtW(const float* __restrict__ W,
                                              u16* __restrict__ Wf) {
  int g = blockIdx.x * 4 + (threadIdx.x >> 6);  // frag id 0..63999
  int l = threadIdx.x & 63;
  int nblk = g >> 5, kb = g & 31;
  const float* src = W + (size_t)(nblk * 16 + (l & 15)) * cH + kb * 32 + (l >> 4) * 8;
  *(short8*)(Wf + (size_t)g * 512 + l * 8) = ldfragW(src);
}

__global__ __launch_bounds__(256) void k_gather(const int* __restrict__ tok,
                                                const float* __restrict__ emb,
                                                u16* __restrict__ dst, int Tlen) {
  int r = blockIdx.x;
  int t = r >> 6, b = r & 63;
  const float* src = emb + (size_t)tok[b * Tlen + t] * cE;
  u16* d = dst + (size_t)r * cE;
  int tid = threadIdx.x;
  for (int k = tid; k < cE; k += 256) d[k] = f2b(src[k]);
}

// ---------- latent / z ----------
__global__ __launch_bounds__(256) void k_latent(
    const u16* __restrict__ encO, const float* __restrict__ cT2,
    const float* __restrict__ W, const float* __restrict__ bias,
    float* __restrict__ mulv, float* __restrict__ outp) {
  __shared__ float s[2 * cH];
  int b = blockIdx.x;
  int n = threadIdx.x;
  for (int k = n; k < cH; k += 256) {
    s[k] = b2f(encO[((size_t)b * cT + 63) * cH + k]);
    s[cH + k] = cT2[b * cH + k];
  }
  __syncthreads();
  float acc = bias[n] + dot_wf(W + (size_t)n * (2 * cH), s, 2 * cH);
  mulv[b * 256 + n] = acc;
  if (n < cZ)
    outp[LOGP_SZ + (size_t)b * cZ + n] = acc;
  else
    outp[LOGP_SZ + (size_t)cB * cZ + (size_t)b * cZ + (n - cZ)] = acc;
}

// latent needs c_T — compute it from the last encoder step's gates + h63:
// Instead we keep c in registers in the coop kernel, so c_T is not in memory.
// Solution: the encoder coop kernel ALSO writes c at the final step.
// (see k_cells_all_enc_c below)

__global__ __launch_bounds__(256) void k_z(const float* __restrict__ mulv,
                                           const float* __restrict__ eps,
                                           u16* __restrict__ zbuf) {
  int i = blockIdx.x * 256 + threadIdx.x;
  if (i >= cB * cZ) return;
  int b = i >> 7, zi = i & 127;
  float mu = mulv[b * 256 + zi], lv = mulv[b * 256 + cZ + zi];
  zbuf[i] = f2b(mu + expf(0.5f * lv) * eps[i]);
}

// ---------- post-hoc: softmax + ctx ----------
__global__ __launch_bounds__(256) void k_sctx(
    const float* __restrict__ S, const int* __restrict__ enc_input,
    const u16* __restrict__ encO, u16* __restrict__ ctxH) {
  __shared__ float wat[cT];
  int tb = blockIdx.x;
  int b = tb & 63;
  int tid = threadIdx.x;
  if (tid < cT) {
    float sc = S[(size_t)tb * cT + tid];
    if (enc_input[b * cT + tid] == cPAD) sc = -INFINITY;
    float m = sc;
#pragma unroll
    for (int off = 32; off >= 1; off >>= 1) m = fmaxf(m, __shfl_xor(m, off));
    float p = expf(sc - m);
    float ssum = p;
#pragma unroll
    for (int off = 32; off >= 1; off >>= 1) ssum += __shfl_xor(ssum, off);
    wat[tid] = p / ssum;
  }
  __syncthreads();
#pragma unroll
  for (int p = 0; p < 4; p++) {
    int j = tid + p * 256;
    float s = 0.f;
    const u16* e = encO + ((size_t)b * cT) * cH + j;
#pragma unroll 8
    for (int t2 = 0; t2 < cT; t2++) s += wat[t2] * b2f(e[(size_t)t2 * cH]);
    ctxH[(size_t)tb * cH + j] = f2b(s);
  }
}

// ---------- post-hoc: kld + aux_c reductions ----------
__global__ __launch_bounds__(256) void k_scal_all(
    const float* __restrict__ priH, const float* __restrict__ infH,
    const u16* __restrict__ ctxH, const u16* __restrict__ auxH,
    const int* __restrict__ length, float* __restrict__ scal) {
  __shared__ float red[256];
  int tb = blockIdx.x;
  int t = tb >> 6, b = tb & 63;
  int tid = threadIdx.x;
  float r = 0.f;
  if (tid < cZ) {
    float pm = priH[(size_t)tb * 256 + tid], plv = priH[(size_t)tb * 256 + cZ + tid];
    float im = infH[(size_t)tb * 256 + tid], ilv = infH[(size_t)tb * 256 + cZ + tid];
    float d = im - pm;
    r = plv - ilv + expf(ilv - plv) + d * d * expf(-plv) - 1.f;
  }
  red[tid] = r;
  __syncthreads();
  for (int sft = 128; sft > 0; sft >>= 1) {
    if (tid < sft) red[tid] += red[tid + sft];
    __syncthreads();
  }
  if (tid == 0 && (length[b] + 1 > t)) atomicAdd(&scal[0], 0.5f * red[0]);
  __syncthreads();
  float r2 = 0.f;
#pragma unroll
  for (int p = 0; p < 4; p++) {
    int j = tid + p * 256;
    float d = b2f(ctxH[(size_t)tb * cH + j]) - b2f(auxH[(size_t)tb * cH + j]);
    r2 += d * d;
  }
  red[tid] = r2;
  __syncthreads();
  for (int sft = 128; sft > 0; sft >>= 1) {
    if (tid < sft) red[tid] += red[tid + sft];
    __syncthreads();
  }
  if (tid == 0) atomicAdd(&scal[1], red[0]);
}

__global__ void k_scal(const float* __restrict__ scal, float* __restrict__ outp) {
  if (threadIdx.x == 0) {
    outp[LOGP_SZ + 2 * cB * cZ] = scal[0];
    outp[LOGP_SZ + 2 * cB * cZ + 1] = scal[1];
  }
}

// copy Amat frag m-blocks [252,260) (256 KB) into d_ws
__global__ __launch_bounds__(256) void k_cpyA(const u16* __restrict__ src,
                                              u16* __restrict__ dst) {
  int i = blockIdx.x * 256 + threadIdx.x;  // 8192 x uint4
  ((uint4*)dst)[i] = ((const uint4*)(src + (size_t)252 * 32 * 512))[i];
}

// ---- output projection v5: N_BLK=64, FULL 128KB W panel staged ONCE, frag A ----
// grid 500, 512 thr (8 waves); wave = 64 rows x 64 cols per m-iter of 512 rows.
template <bool WFRAG>
__global__ __launch_bounds__(512) void k_logit5(
    const u16* __restrict__ Af, int fragBase,
    const u16* __restrict__ Wf, const float* __restrict__ Wraw,
    const float* __restrict__ bias, float* __restrict__ outp,
    int mStart, int mEnd, int storeLo, int storeHi, int skipLo, int skipHi) {
  __shared__ u16 wpan[65536];  // 128 KB: [f(128)][512], f = fr*32+kb
  int nb = blockIdx.x;         // 0..499 (64 cols each)
  int tid = threadIdx.x;
  if constexpr (WFRAG) {
    const uint4* src = (const uint4*)(Wf + (size_t)nb * 65536);
    uint4* dst = (uint4*)wpan;
#pragma unroll
    for (int q = 0; q < 16; q++) dst[tid + q * 512] = src[tid + q * 512];
  } else {
    int wv = tid >> 6, l = tid & 63;
    for (int f = wv; f < 128; f += 8) {
      int fr = f >> 5, kb = f & 31;
      const float* src = Wraw + (size_t)(nb * 64 + fr * 16 + (l & 15)) * cH + kb * 32 + (l >> 4) * 8;
      *(short8*)(wpan + (size_t)f * 512 + l * 8) = ldfragW(src);
    }
  }
  __syncthreads();
  int wave = tid >> 6, lane = tid & 63;
  int lr = lane & 15, kg = lane >> 4;
  for (int m0 = mStart; m0 < mEnd; m0 += 512) {
    int mi = m0 + wave * 64;
    int mfg[4];
#pragma unroll
    for (int mf = 0; mf < 4; mf++) {
      int g = (mi >> 4) + mf;
      if (g > 259) g = 259;
      mfg[mf] = g - fragBase;
    }
    floatx4 acc[4][4];
#pragma unroll
    for (int mf = 0; mf < 4; mf++)
#pragma unroll
      for (int fr = 0; fr < 4; fr++) acc[mf][fr] = (floatx4){0.f, 0.f, 0.f, 0.f};
#pragma unroll 2
    for (int ks = 0; ks < 32; ks++) {
      short8 bv[4];
#pragma unroll
      for (int fr = 0; fr < 4; fr++)
        bv[fr] = *(const short8*)(wpan + ((size_t)(fr * 32 + ks) * 512) + lane * 8);
#pragma unroll
      for (int mf = 0; mf < 4; mf++) {
        short8 av = *(const short8*)(Af + ((size_t)mfg[mf] * 32 + ks) * 512 + lane * 8);
#pragma unroll
        for (int fr = 0; fr < 4; fr++)
          acc[mf][fr] = __builtin_amdgcn_mfma_f32_16x16x32_bf16(av, bv[fr], acc[mf][fr], 0, 0, 0);
      }
    }
#pragma unroll
    for (int mf = 0; mf < 4; mf++) {
#pragma unroll
      for (int fr = 0; fr < 4; fr++) {
        int n = nb * 64 + fr * 16 + lr;
        float bb = bias[n];
#pragma unroll
        for (int jj = 0; jj < 4; jj++) {
          int m = mi + mf * 16 + kg * 4 + jj;
          if (m >= storeLo && m < storeHi && !(m >= skipLo && m < skipHi))
            outp[(size_t)m * cV + n] = acc[mf][fr][jj] + bb;
        }
      }
    }
  }
}

// ---- row log-softmax, 2-pass online ----
__global__ __launch_bounds__(256) void k_lsm(float* __restrict__ outp) {
  __shared__ float wm_[4], ws_[4];
  __shared__ float blz;
  int m = blockIdx.x;
  int tid = threadIdx.x, lane = tid & 63, wid = tid >> 6;
  float4* rp4 = (float4*)(outp + (size_t)m * cV);
  float mx = -INFINITY, sm = 0.f;
  for (int n = tid; n < cV / 4; n += 256) {
    float4 v = rp4[n];
    float lm = fmaxf(fmaxf(v.x, v.y), fmaxf(v.z, v.w));
    float nm = fmaxf(mx, lm);
    sm = sm * expf(mx - nm) + expf(v.x - nm) + expf(v.y - nm) + expf(v.z - nm) + expf(v.w - nm);
    mx = nm;
  }
#pragma unroll
  for (int off = 32; off >= 1; off >>= 1) {
    float om = __shfl_xor(mx, off), os = __shfl_xor(sm, off);
    float nm = fmaxf(mx, om);
    sm = sm * expf(mx - nm) + os * expf(om - nm);
    mx = nm;
  }
  if (lane == 0) { wm_[wid] = mx; ws_[wid] = sm; }
  __syncthreads();
  if (tid == 0) {
    float M = fmaxf(fmaxf(wm_[0], wm_[1]), fmaxf(wm_[2], wm_[3]));
    float S = ws_[0] * expf(wm_[0] - M) + ws_[1] * expf(wm_[1] - M) +
              ws_[2] * expf(wm_[2] - M) + ws_[3] * expf(wm_[3] - M);
    blz = M + logf(S);
  }
  __syncthreads();
  float lz = blz;
  for (int n = tid; n < cV / 4; n += 256) {
    float4 v = rp4[n];
    v.x -= lz; v.y -= lz; v.z -= lz; v.w -= lz;
    rp4[n] = v;
  }
}

// encoder final-step c writer: recompute c_T is avoided by having the coop encoder
// write c at its last step. We pass cOut and write when t == NSTEPS-1.
template <int NSTEPS>
__global__ __launch_bounds__(64) void k_cells_enc(
    const u16* __restrict__ G, const u16* __restrict__ H0,
    const u16* __restrict__ Wb, u16* __restrict__ Hist,
    float* __restrict__ cOut) {
  cg::grid_group grid = cg::this_grid();
  int nb = blockIdx.x;
  int lane = threadIdx.x;
  int lr = lane & 15, kg = lane >> 4;
  __shared__ u16 wpan[16384];
  __shared__ float ldsT[16][65];
  {
    const u16* src = Wb + (size_t)(nb * 16 + lr) * cH + kg * 8;
#pragma unroll 4
    for (int ks = 0; ks < 32; ks++)
      *(short8*)(wpan + ks * 512 + lane * 8) = *(const short8*)(src + ks * 32);
  }
  float creg[4] = {0.f, 0.f, 0.f, 0.f};
  __syncthreads();
  for (int t = 0; t < NSTEPS; t++) {
    const u16* H = t ? (Hist + (size_t)(t - 1) * cH) : H0;
    int strideH = t ? (cT * cH) : cH;
    floatx4 acc[4];
#pragma unroll
    for (int mf = 0; mf < 4; mf++) acc[mf] = (floatx4){0.f, 0.f, 0.f, 0.f};
#pragma unroll 8
    for (int ks = 0; ks < 32; ks++) {
      short8 bv = *(const short8*)(wpan + ks * 512 + lane * 8);
#pragma unroll
      for (int mf = 0; mf < 4; mf++) {
        short8 av = *(const short8*)(H + (size_t)(mf * 16 + lr) * strideH + ks * 32 + kg * 8);
        acc[mf] = __builtin_amdgcn_mfma_f32_16x16x32_bf16(av, bv, acc[mf], 0, 0, 0);
      }
    }
#pragma unroll
    for (int mf = 0; mf < 4; mf++)
#pragma unroll
      for (int jj = 0; jj < 4; jj++)
        ldsT[lr][mf * 16 + kg * 4 + jj] = acc[mf][jj];
    __syncthreads();
    int b = lane;
    const u16* gp = G + ((size_t)t * cB + b) * 4096 + nb * 16;
    u16 hb[4];
#pragma unroll
    for (int a = 0; a < 4; a++) {
      ushort4 gv = *(const ushort4*)(gp + 4 * a);
      float gi = ldsT[4 * a + 0][b] + b2f(gv.x);
      float gf = ldsT[4 * a + 1][b] + b2f(gv.y);
      float gg = ldsT[4 * a + 2][b] + b2f(gv.z);
      float go = ldsT[4 * a + 3][b] + b2f(gv.w);
      float cc = creg[a];
      cc = sigm(gf) * cc + sigm(gi) * tanhf(gg);
      float hh = sigm(go) * tanhf(cc);
      creg[a] = cc;
      hb[a] = f2b(hh);
    }
    ushort4 hv = {hb[0], hb[1], hb[2], hb[3]};
    int j0 = nb * 4;
    *(ushort4*)(Hist + (size_t)b * (cT * cH) + (size_t)t * cH + j0) = hv;
    if (t == NSTEPS - 1)
      *(float4*)(cOut + (size_t)b * cH + j0) =
          make_float4(creg[0], creg[1], creg[2], creg[3]);
    __syncthreads();
    grid.sync();
  }
}

extern "C" void kernel_launch(void* const* d_in, const int* in_sizes, int n_in,
                              void* d_out, int out_size, void* d_ws, size_t ws_size,
                              hipStream_t stream) {
  (void)in_sizes; (void)n_in; (void)out_size; (void)ws_size;
  const int* enc_input  = (const int*)d_in[0];
  const int* dec_input  = (const int*)d_in[1];
  const int* length     = (const int*)d_in[2];
  const float* eps      = (const float*)d_in[3];
  const float* enc_emb  = (const float*)d_in[4];
  const float* enc_Wih  = (const float*)d_in[5];
  const float* enc_Whh  = (const float*)d_in[6];
  const float* enc_bih  = (const float*)d_in[7];
  const float* enc_bhh  = (const float*)d_in[8];
  const float* latent_W = (const float*)d_in[9];
  const float* latent_b = (const float*)d_in[10];
  const float* dec_emb  = (const float*)d_in[11];
  const float* attn_W   = (const float*)d_in[12];
  const float* attn_b   = (const float*)d_in[13];
  const float* comb_W   = (const float*)d_in[14];
  const float* comb_b   = (const float*)d_in[15];
  const float* dec_Wih  = (const float*)d_in[16];
  const float* dec_Whh  = (const float*)d_in[17];
  const float* dec_bih  = (const float*)d_in[18];
  const float* dec_bhh  = (const float*)d_in[19];
  const float* pri_W    = (const float*)d_in[20];
  const float* pri_b    = (const float*)d_in[21];
  const float* inf_W    = (const float*)d_in[22];
  const float* inf_b    = (const float*)d_in[23];
  const float* aux_W    = (const float*)d_in[24];
  const float* aux_b    = (const float*)d_in[25];
  const float* out_W    = (const float*)d_in[26];
  const float* out_b    = (const float*)d_in[27];
  float* outp = (float*)d_out;
  float* outF = outp;

  // ---- scratch layout in logp head (R10-proven) ----
  size_t off = 0;
  float* c_enc = outF + off; off += 65536;   // c_T output of encoder coop kernel
  float* c_dec = outF + off; off += 65536;   // unused (decoder c in registers)
  float* scal  = outF + off; off += 4;
  off += 60;
  u16* HencZ = (u16*)(outF + off); off += 32768;
  u16* Hh    = (u16*)(outF + off); off += 66 * 32768;
  size_t zeroSpan = 196672;
  u16* encO  = (u16*)(outF + off); off += 2097152;
  u16* Xenc  = (u16*)(outF + off); off += 1048576;
  u16* Xdec  = (u16*)(outF + off); off += 1064960;
  u16* zbuf  = (u16*)(outF + off); off += 4096;
  float* mulv  = outF + off; off += 16384;
  float* biasE = outF + off; off += 4096;
  float* biasD = outF + off; off += 4096;
  float* tmp1  = outF + off; off += 1024;
  float* u0    = outF + off; off += 1024;
  float* WcxT  = outF + off; off += 524288;
  float* WczT  = outF + off; off += 131072;
  float* wPmT  = outF + off; off += 131072;
  float* auxWT = outF + off; off += 131072;
  float* M1    = outF + off; off += 131072;
  float* WfT   = outF + off; off += 1048576;
  u16* WhhEp = (u16*)(outF + off); off += 2097152;
  u16* Wbig  = (u16*)(outF + off); off += 2097152;
  u16* C1    = (u16*)(outF + off); off += 1048576;
  u16* C2    = (u16*)(outF + off); off += 262144;
  u16* Genc  = (u16*)(outF + off); off += 8388608;
  u16* Gdec  = (u16*)(outF + off); off += 8519680;
  float* priH = outF + off; off += 1064960;
  float* infH = outF + off; off += 1064960;
  float* S    = outF + off; off += 266240;
  u16* ctxH  = (u16*)(outF + off); off += 2129920;
  u16* auxH  = (u16*)(outF + off); off += 2129920;  // ends ~37.7M < 38.4M
  u16* Wf   = (u16*)(outF + WBOUT_OFF);
  u16* Amat = (u16*)(outF + AMAT_OFF);
  u16* wsA = (u16*)d_ws;

  // ---- prep ----
  k_cvtW<<<16000, 256, 0, stream>>>(out_W, Wf);
  k_tr<<<dim3(16, 32), 256, 0, stream>>>(comb_W, 1792, 1024, WcxT);
  k_tr<<<dim3(4, 32), 256, 0, stream>>>(comb_W + 1664, 1792, 1024, WczT);
  k_tr<<<dim3(32, 4), 256, 0, stream>>>(pri_W, 1024, 128, wPmT);
  k_tr<<<dim3(4, 32), 256, 0, stream>>>(aux_W, 128, 1024, auxWT);
  k_gemv<<<4, 256, 0, stream>>>(aux_W, 128, pri_b, aux_b, tmp1, 128, 0);
  k_gemv<<<4, 256, 0, stream>>>(comb_W + 512, 1792, tmp1, comb_b, u0, 1024, 0);
  k_gemv<<<4, 256, 0, stream>>>(comb_W + 1536, 1792, pri_b, nullptr, u0, 128, 1);
  k_biasE<<<16, 256, 0, stream>>>(enc_bih, enc_bhh, biasE);
  k_biasD<<<16, 256, 0, stream>>>(dec_bih, dec_bhh, dec_Wih, u0, biasD);
  k_permW<<<4096, 256, 0, stream>>>(enc_Whh, WhhEp);
  k_gather<<<cT * cB, 256, 0, stream>>>(enc_input, enc_emb, Xenc, cT);
  k_gather<<<cTP1 * cB, 256, 0, stream>>>(dec_input, dec_emb, Xdec, cTP1);
  k_zero<<<(int)((zeroSpan + 255) / 256), 256, 0, stream>>>(c_enc, (int)zeroSpan);

  // ---- weight composition (R10-proven) ----
  k_gemm<float, float, float, 0, 0, false><<<dim3(8, 16), 64, 0, stream>>>(
      comb_W + 512, 1792, auxWT, 1024, nullptr, comb_W + 1536, 1792, M1, 128, 1024);
  k_gemm<float, float, float, 0, 0, false><<<dim3(64, 16), 64, 0, stream>>>(
      wPmT, 128, M1, 128, nullptr, nullptr, 0, WfT, 1024, 128);
  k_gemm<float, float, u16, 1, 0, false><<<dim3(64, 64), 64, 0, stream>>>(
      dec_Wih, 1024, WfT, 1024, nullptr, dec_Whh, 1024, Wbig, 1024, 1024);
  k_gemm<float, float, u16, 1, 0, false><<<dim3(32, 64), 64, 0, stream>>>(
      dec_Wih, 1024, WcxT, 1024, nullptr, nullptr, 0, C1, 512, 1024);
  k_gemm<float, float, u16, 1, 0, false><<<dim3(8, 64), 64, 0, stream>>>(
      dec_Wih, 1024, WczT, 1024, nullptr, nullptr, 0, C2, 128, 1024);
  k_gemm<u16, float, u16, 0, 1, false><<<dim3(256, 64), 64, 0, stream>>>(
      Xenc, 512, enc_Wih, 512, biasE, nullptr, 0, Genc, 4096, 512);

  // ---- encoder: ONE cooperative kernel, 64 steps ----
  {
    void (*fn)(const u16*, const u16*, const u16*, u16*, float*) = k_cells_enc<cT>;
    void* args[] = {(void*)&Genc, (void*)&HencZ, (void*)&WhhEp, (void*)&encO, (void*)&c_enc};
    hipLaunchCooperativeKernel(reinterpret_cast<void*>(fn), dim3(256), dim3(64),
                               args, 0, stream);
  }
  k_latent<<<cB, 256, 0, stream>>>(encO, c_enc, latent_W, latent_b, mulv, outp);
  k_z<<<(cB * cZ + 255) / 256, 256, 0, stream>>>(mulv, eps, zbuf);

  // ---- Gdec ----
  k_gemm<u16, u16, u16, 0, 0, false><<<dim3(256, 65), 64, 0, stream>>>(
      Xdec, 512, C1, 512, biasD, nullptr, 0, Gdec, 4096, 512);
  k_gemm<u16, u16, u16, 2, 0, true><<<dim3(256, 65), 64, 0, stream>>>(
      zbuf, 128, C2, 128, nullptr, nullptr, 0, Gdec, 4096, 128);

  // ---- decoder: ONE cooperative kernel, 65 steps ----
  {
    void (*fn)(const u16*, const u16*, const u16*, u16*, u16*) = k_cells_all<cTP1, true>;
    u16* nullH = nullptr;
    void* args[] = {(void*)&Gdec, (void*)&nullH, (void*)&Wbig, (void*)&Hh, (void*)&Amat};
    hipLaunchCooperativeKernel(reinterpret_cast<void*>(fn), dim3(256), dim3(64),
                               args, 0, stream);
  }

  // ---- post-hoc batched math ----
  k_gemm<u16, float, float, 0, 0, false><<<dim3(16, 65), 64, 0, stream>>>(
      Hh, 1024, pri_W, 1024, pri_b, nullptr, 0, priH, 256, 1024);
  k_gemm<u16, float, float, 0, 0, false><<<dim3(4, 65), 64, 0, stream>>>(
      Xdec, 512, attn_W, 1536, attn_b, nullptr, 0, S, 64, 512);
  k_gemm<u16, float, float, 0, 0, true><<<dim3(4, 65), 64, 0, stream>>>(
      Hh, 1024, attn_W + 512, 1536, nullptr, nullptr, 0, S, 64, 1024);
  k_sctx<<<cTP1 * cB, 256, 0, stream>>>(S, enc_input, encO, ctxH);
  k_gemm<u16, float, float, 0, 0, false><<<dim3(16, 65), 64, 0, stream>>>(
      Hh, 1024, inf_W, 2048, inf_b, nullptr, 0, infH, 256, 1024);
  k_gemm<u16, float, float, 0, 0, true><<<dim3(16, 65), 64, 0, stream>>>(
      ctxH, 1024, inf_W + 1024, 2048, nullptr, nullptr, 0, infH, 256, 1024);
  k_gemm<float, float, u16, 0, 0, false><<<dim3(64, 65), 64, 0, stream>>>(
      priH, 256, aux_W, 128, aux_b, nullptr, 0, auxH, 1024, 128);
  k_scal_all<<<cTP1 * cB, 256, 0, stream>>>(priH, infH, ctxH, auxH, length, scal);
  k_scal<<<1, 64, 0, stream>>>(scal, outp);

  // ---- output projection (N_BLK=64, stage once) + log-softmax ----
  k_cpyA<<<32, 256, 0, stream>>>(Amat, wsA);
  k_logit5<true><<<500, 512, 0, stream>>>(Amat, 0, Wf, nullptr, out_b, outp,
                                          0, 4096, 0, 4093, SKIP_LO, SKIP_HI);
  k_logit5<false><<<500, 512, 0, stream>>>(Amat, 0, nullptr, out_W, out_b, outp,
                                           SKIP_LO, SKIP_HI, SKIP_LO, SKIP_HI, 0, 0);
  k_logit5<false><<<500, 512, 0, stream>>>(wsA, 252, nullptr, out_W, out_b, outp,
                                           4032, 4160, 4093, 4160, 0, 0);
  k_lsm<<<cB * cTP1, 256, 0, stream>>>(outp);
}

// Round 14
// 3974.007 us; speedup vs baseline: 1.9169x; 1.9169x over previous
//
#include <hip/hip_runtime.h>
#include <hip/hip_bf16.h>
#include <cmath>

typedef unsigned short u16;
typedef __attribute__((ext_vector_type(8))) short short8;
typedef __attribute__((ext_vector_type(4))) float floatx4;

#define DEVI __device__ __forceinline__

constexpr int cV = 32000, cE = 512, cT = 64, cH = 1024, cZ = 128, cB = 64, cPAD = 31999, cTP1 = 65;
constexpr long long LOGP_SZ = 133120000LL;   // B*(T+1)*V f32 elems
constexpr long long AMAT_OFF = 130990080LL;  // logp tail: 260 frag-rows x 32 x 512 u16
constexpr long long WBOUT_OFF = 38400000LL;  // logp rows [1200,1712): frag bf16 out_W
constexpr int SKIP_LO = 1200, SKIP_HI = 1712;

DEVI float b2f(u16 u) { return __uint_as_float(((unsigned)u) << 16); }
DEVI u16 f2b(float f) {
  unsigned u = __float_as_uint(f);
  unsigned r = u + 0x7FFFu + ((u >> 16) & 1u);
  return (u16)(r >> 16);
}
DEVI unsigned pk2(float lo, float hi) {
  __hip_bfloat162 t = __float22bfloat162_rn(make_float2(lo, hi));
  return *reinterpret_cast<unsigned*>(&t);
}
DEVI float sigm(float x) { return 1.f / (1.f + expf(-x)); }

DEVI short8 ldfragW(const float* __restrict__ p) {
  float4 x = *(const float4*)p, y = *(const float4*)(p + 4);
  union { unsigned u[4]; short8 s; } r;
  r.u[0] = pk2(x.x, x.y); r.u[1] = pk2(x.z, x.w);
  r.u[2] = pk2(y.x, y.y); r.u[3] = pk2(y.z, y.w);
  return r.s;
}

template <typename T>
DEVI short8 ldfrag(const T* __restrict__ p) {
  if constexpr (sizeof(T) == 2) return *(const short8*)(p);
  else return ldfragW((const float*)p);
}

template <int MAP>
DEVI int rmap(int r) {
  if constexpr (MAP == 1) return ((r & 3) << 10) | (r >> 2);
  else if constexpr (MAP == 2) return r & 63;
  else return r;
}

DEVI float dot_wf(const float* __restrict__ w, const float* __restrict__ s, int K) {
  float a0 = 0.f, a1 = 0.f, a2 = 0.f, a3 = 0.f;
#pragma unroll 4
  for (int k = 0; k < K; k += 8) {
    float4 p = *(const float4*)(w + k);
    float4 q = *(const float4*)(w + k + 4);
    a0 = fmaf(s[k + 0], p.x, a0); a1 = fmaf(s[k + 1], p.y, a1);
    a2 = fmaf(s[k + 2], p.z, a2); a3 = fmaf(s[k + 3], p.w, a3);
    a0 = fmaf(s[k + 4], q.x, a0); a1 = fmaf(s[k + 5], q.y, a1);
    a2 = fmaf(s[k + 6], q.z, a2); a3 = fmaf(s[k + 7], q.w, a3);
  }
  return (a0 + a1) + (a2 + a3);
}

__global__ __launch_bounds__(256) void k_zero(float* p, int n) {
  int i = blockIdx.x * 256 + threadIdx.x;
  if (i < n) p[i] = 0.f;
}

// ---------- generic MFMA GEMM (prep/post-hoc paths, proven) ----------
template <typename AT, typename BT, typename CT, int AMAP, int BMAP, bool ADDC>
__global__ __launch_bounds__(64) void k_gemm(
    const AT* __restrict__ A, int lda, const BT* __restrict__ B, int ldb,
    const float* __restrict__ bias, const float* __restrict__ Dm, int ldd,
    CT* __restrict__ C, int ldc, int K) {
  int nblk = blockIdx.x, mblk = blockIdx.y;
  int lane = threadIdx.x;
  int lr = lane & 15, kg = lane >> 4;
  const BT* Bp = B + (size_t)rmap<BMAP>(nblk * 16 + lr) * ldb + kg * 8;
  const AT* Ap[4];
#pragma unroll
  for (int mf = 0; mf < 4; mf++)
    Ap[mf] = A + (size_t)rmap<AMAP>(mblk * 64 + mf * 16 + lr) * lda + kg * 8;
  floatx4 acc[4];
#pragma unroll
  for (int mf = 0; mf < 4; mf++) acc[mf] = (floatx4){0.f, 0.f, 0.f, 0.f};
#pragma unroll 4
  for (int ks = 0; ks < K / 32; ks++) {
    short8 bv = ldfrag(Bp + ks * 32);
#pragma unroll
    for (int mf = 0; mf < 4; mf++) {
      short8 av = ldfrag(Ap[mf] + ks * 32);
      acc[mf] = __builtin_amdgcn_mfma_f32_16x16x32_bf16(av, bv, acc[mf], 0, 0, 0);
    }
  }
  int n = nblk * 16 + lr;
  float bs = bias ? bias[n] : 0.f;
#pragma unroll
  for (int mf = 0; mf < 4; mf++) {
#pragma unroll
    for (int jj = 0; jj < 4; jj++) {
      int m = mblk * 64 + mf * 16 + kg * 4 + jj;
      size_t ci = (size_t)m * ldc + n;
      float v = acc[mf][jj] + bs;
      if (Dm) v += Dm[(size_t)rmap<AMAP>(m) * ldd + n];
      if constexpr (ADDC) {
        if constexpr (sizeof(CT) == 2) v += b2f(C[ci]);
        else v += C[ci];
      }
      if constexpr (sizeof(CT) == 2) C[ci] = f2b(v);
      else C[ci] = v;
    }
  }
}

// ---------- serial step: gates = G[t] + Wbig x h; LSTM cell; frag-scatter h ----------
__global__ __launch_bounds__(64) void k_cell2(
    const u16* __restrict__ G, const u16* __restrict__ H, int strideH,
    const u16* __restrict__ Wb, float* __restrict__ c,
    u16* __restrict__ out1, int s1, u16* __restrict__ Afrag, int t) {
  int nb = blockIdx.x;
  int lane = threadIdx.x;
  int lr = lane & 15, kg = lane >> 4;
  const u16* Bp = Wb + (size_t)(nb * 16 + lr) * cH + kg * 8;
  floatx4 acc[4];
#pragma unroll
  for (int mf = 0; mf < 4; mf++) acc[mf] = (floatx4){0.f, 0.f, 0.f, 0.f};
#pragma unroll 8
  for (int ks = 0; ks < 32; ks++) {
    short8 bv = *(const short8*)(Bp + ks * 32);
#pragma unroll
    for (int mf = 0; mf < 4; mf++) {
      short8 av = *(const short8*)(H + (size_t)(mf * 16 + lr) * strideH + ks * 32 + kg * 8);
      acc[mf] = __builtin_amdgcn_mfma_f32_16x16x32_bf16(av, bv, acc[mf], 0, 0, 0);
    }
  }
  __shared__ float lds[16][65];
#pragma unroll
  for (int mf = 0; mf < 4; mf++)
#pragma unroll
    for (int jj = 0; jj < 4; jj++)
      lds[lr][mf * 16 + kg * 4 + jj] = acc[mf][jj];
  __syncthreads();
#pragma unroll
  for (int a = 0; a < 4; a++) {
    int b = lane;
    int j = nb * 4 + a;
    ushort4 gv = *(const ushort4*)(G + (size_t)b * 4096 + nb * 16 + 4 * a);
    float gi = lds[4 * a + 0][b] + b2f(gv.x);
    float gf = lds[4 * a + 1][b] + b2f(gv.y);
    float gg = lds[4 * a + 2][b] + b2f(gv.z);
    float go = lds[4 * a + 3][b] + b2f(gv.w);
    int ci = b * cH + j;
    float cc = c[ci];
    cc = sigm(gf) * cc + sigm(gi) * tanhf(gg);
    float hh = sigm(go) * tanhf(cc);
    c[ci] = cc;
    u16 hb = f2b(hh);
    out1[(size_t)b * s1 + j] = hb;
    if (Afrag) {
      int m = b * cTP1 + t;
      size_t idx = ((size_t)(m >> 4) * 32 + (j >> 5)) * 512 +
                   ((((j >> 3) & 3) * 16) + (m & 15)) * 8 + (j & 7);
      Afrag[idx] = hb;
    }
  }
}

// ---------- small prep kernels ----------
__global__ __launch_bounds__(256) void k_tr(const float* __restrict__ src, int ld,
                                            int R, float* __restrict__ dst) {
  __shared__ float tile[32][33];
  int c0 = blockIdx.x * 32, r0 = blockIdx.y * 32;
  int tx = threadIdx.x & 31, ty = threadIdx.x >> 5;
  for (int i = ty; i < 32; i += 8) tile[i][tx] = src[(size_t)(r0 + i) * ld + c0 + tx];
  __syncthreads();
  for (int i = ty; i < 32; i += 8) dst[(size_t)(c0 + i) * R + r0 + tx] = tile[tx][i];
}

__global__ __launch_bounds__(256) void k_gemv(const float* __restrict__ W, int ld,
                                              const float* __restrict__ x,
                                              const float* __restrict__ b,
                                              float* __restrict__ out, int K, int add) {
  int n = blockIdx.x * 256 + threadIdx.x;
  const float* w = W + (size_t)n * ld;
  float s = b ? b[n] : 0.f;
  for (int k = 0; k < K; k += 4) {
    float4 wv = *(const float4*)(w + k);
    float4 xv = *(const float4*)(x + k);
    s += wv.x * xv.x + wv.y * xv.y + wv.z * xv.z + wv.w * xv.w;
  }
  if (add) out[n] += s; else out[n] = s;
}

__global__ __launch_bounds__(256) void k_biasD(const float* __restrict__ bih,
                                               const float* __restrict__ bhh,
                                               const float* __restrict__ Wih,
                                               const float* __restrict__ u0,
                                               float* __restrict__ biasD) {
  int np = blockIdx.x * 256 + threadIdx.x;
  int src = ((np & 3) << 10) | (np >> 2);
  const float* w = Wih + (size_t)src * cH;
  float s = bih[src] + bhh[src];
  for (int k = 0; k < cH; k += 4) {
    float4 wv = *(const float4*)(w + k);
    float4 xv = *(const float4*)(u0 + k);
    s += wv.x * xv.x + wv.y * xv.y + wv.z * xv.z + wv.w * xv.w;
  }
  biasD[np] = s;
}

__global__ __launch_bounds__(256) void k_biasE(const float* __restrict__ bih,
                                               const float* __restrict__ bhh,
                                               float* __restrict__ biasE) {
  int np = blockIdx.x * 256 + threadIdx.x;
  int src = ((np & 3) << 10) | (np >> 2);
  biasE[np] = bih[src] + bhh[src];
}

__global__ __launch_bounds__(256) void k_permW(const float* __restrict__ Whh,
                                               u16* __restrict__ Wp) {
  int np = blockIdx.x;
  int src = ((np & 3) << 10) | (np >> 2);
  const float* w = Whh + (size_t)src * cH;
  u16* d = Wp + (size_t)np * cH;
  int tid = threadIdx.x;
#pragma unroll
  for (int p = 0; p < 4; p++) d[tid + p * 256] = f2b(w[tid + p * 256]);
}

// out_W (f32 row-major) -> frag-linear bf16: one wave per 16x32 frag
__global__ __launch_bounds__(256) void k_cvtW(const float* __restrict__ W,
                                              u16* __restrict__ Wf) {
  int g = blockIdx.x * 4 + (threadIdx.x >> 6);  // frag id 0..63999
  int l = threadIdx.x & 63;
  int nblk = g >> 5, kb = g & 31;
  const float* src = W + (size_t)(nblk * 16 + (l & 15)) * cH + kb * 32 + (l >> 4) * 8;
  *(short8*)(Wf + (size_t)g * 512 + l * 8) = ldfragW(src);
}

__global__ __launch_bounds__(256) void k_gather(const int* __restrict__ tok,
                                                const float* __restrict__ emb,
                                                u16* __restrict__ dst, int Tlen) {
  int r = blockIdx.x;
  int t = r >> 6, b = r & 63;
  const float* src = emb + (size_t)tok[b * Tlen + t] * cE;
  u16* d = dst + (size_t)r * cE;
  int tid = threadIdx.x;
  for (int k = tid; k < cE; k += 256) d[k] = f2b(src[k]);
}

// ---------- latent / z ----------
__global__ __launch_bounds__(256) void k_latent(
    const u16* __restrict__ encO, const float* __restrict__ cT2,
    const float* __restrict__ W, const float* __restrict__ bias,
    float* __restrict__ mulv, float* __restrict__ outp) {
  __shared__ float s[2 * cH];
  int b = blockIdx.x;
  int n = threadIdx.x;
  for (int k = n; k < cH; k += 256) {
    s[k] = b2f(encO[((size_t)b * cT + 63) * cH + k]);
    s[cH + k] = cT2[b * cH + k];
  }
  __syncthreads();
  float acc = bias[n] + dot_wf(W + (size_t)n * (2 * cH), s, 2 * cH);
  mulv[b * 256 + n] = acc;
  if (n < cZ)
    outp[LOGP_SZ + (size_t)b * cZ + n] = acc;
  else
    outp[LOGP_SZ + (size_t)cB * cZ + (size_t)b * cZ + (n - cZ)] = acc;
}

__global__ __launch_bounds__(256) void k_z(const float* __restrict__ mulv,
                                           const float* __restrict__ eps,
                                           u16* __restrict__ zbuf) {
  int i = blockIdx.x * 256 + threadIdx.x;
  if (i >= cB * cZ) return;
  int b = i >> 7, zi = i & 127;
  float mu = mulv[b * 256 + zi], lv = mulv[b * 256 + cZ + zi];
  zbuf[i] = f2b(mu + expf(0.5f * lv) * eps[i]);
}

// ---------- post-hoc: softmax + ctx ----------
__global__ __launch_bounds__(256) void k_sctx(
    const float* __restrict__ S, const int* __restrict__ enc_input,
    const u16* __restrict__ encO, u16* __restrict__ ctxH) {
  __shared__ float wat[cT];
  int tb = blockIdx.x;
  int b = tb & 63;
  int tid = threadIdx.x;
  if (tid < cT) {
    float sc = S[(size_t)tb * cT + tid];
    if (enc_input[b * cT + tid] == cPAD) sc = -INFINITY;
    float m = sc;
#pragma unroll
    for (int off = 32; off >= 1; off >>= 1) m = fmaxf(m, __shfl_xor(m, off));
    float p = expf(sc - m);
    float ssum = p;
#pragma unroll
    for (int off = 32; off >= 1; off >>= 1) ssum += __shfl_xor(ssum, off);
    wat[tid] = p / ssum;
  }
  __syncthreads();
#pragma unroll
  for (int p = 0; p < 4; p++) {
    int j = tid + p * 256;
    float s = 0.f;
    const u16* e = encO + ((size_t)b * cT) * cH + j;
#pragma unroll 8
    for (int t2 = 0; t2 < cT; t2++) s += wat[t2] * b2f(e[(size_t)t2 * cH]);
    ctxH[(size_t)tb * cH + j] = f2b(s);
  }
}

// ---------- post-hoc: kld + aux_c reductions ----------
__global__ __launch_bounds__(256) void k_scal_all(
    const float* __restrict__ priH, const float* __restrict__ infH,
    const u16* __restrict__ ctxH, const u16* __restrict__ auxH,
    const int* __restrict__ length, float* __restrict__ scal) {
  __shared__ float red[256];
  int tb = blockIdx.x;
  int t = tb >> 6, b = tb & 63;
  int tid = threadIdx.x;
  float r = 0.f;
  if (tid < cZ) {
    float pm = priH[(size_t)tb * 256 + tid], plv = priH[(size_t)tb * 256 + cZ + tid];
    float im = infH[(size_t)tb * 256 + tid], ilv = infH[(size_t)tb * 256 + cZ + tid];
    float d = im - pm;
    r = plv - ilv + expf(ilv - plv) + d * d * expf(-plv) - 1.f;
  }
  red[tid] = r;
  __syncthreads();
  for (int sft = 128; sft > 0; sft >>= 1) {
    if (tid < sft) red[tid] += red[tid + sft];
    __syncthreads();
  }
  if (tid == 0 && (length[b] + 1 > t)) atomicAdd(&scal[0], 0.5f * red[0]);
  __syncthreads();
  float r2 = 0.f;
#pragma unroll
  for (int p = 0; p < 4; p++) {
    int j = tid + p * 256;
    float d = b2f(ctxH[(size_t)tb * cH + j]) - b2f(auxH[(size_t)tb * cH + j]);
    r2 += d * d;
  }
  red[tid] = r2;
  __syncthreads();
  for (int sft = 128; sft > 0; sft >>= 1) {
    if (tid < sft) red[tid] += red[tid + sft];
    __syncthreads();
  }
  if (tid == 0) atomicAdd(&scal[1], red[0]);
}

__global__ void k_scal(const float* __restrict__ scal, float* __restrict__ outp) {
  if (threadIdx.x == 0) {
    outp[LOGP_SZ + 2 * cB * cZ] = scal[0];
    outp[LOGP_SZ + 2 * cB * cZ + 1] = scal[1];
  }
}

// copy Amat frag m-blocks [252,260) (256 KB) into d_ws
__global__ __launch_bounds__(256) void k_cpyA(const u16* __restrict__ src,
                                              u16* __restrict__ dst) {
  int i = blockIdx.x * 256 + threadIdx.x;  // 8192 x uint4
  ((uint4*)dst)[i] = ((const uint4*)(src + (size_t)252 * 32 * 512))[i];
}

// ---- output projection v5: N_BLK=64, FULL 128KB W panel staged ONCE, frag A ----
// grid 500, 512 thr (8 waves); wave = 64 rows x 64 cols per m-iter of 512 rows.
template <bool WFRAG>
__global__ __launch_bounds__(512) void k_logit5(
    const u16* __restrict__ Af, int fragBase,
    const u16* __restrict__ Wf, const float* __restrict__ Wraw,
    const float* __restrict__ bias, float* __restrict__ outp,
    int mStart, int mEnd, int storeLo, int storeHi, int skipLo, int skipHi) {
  __shared__ u16 wpan[65536];  // 128 KB: [f(128)][512], f = fr*32+kb
  int nb = blockIdx.x;
  int tid = threadIdx.x;
  if constexpr (WFRAG) {
    const uint4* src = (const uint4*)(Wf + (size_t)nb * 65536);
    uint4* dst = (uint4*)wpan;
#pragma unroll
    for (int q = 0; q < 16; q++) dst[tid + q * 512] = src[tid + q * 512];
  } else {
    int wv = tid >> 6, l = tid & 63;
    for (int f = wv; f < 128; f += 8) {
      int fr = f >> 5, kb = f & 31;
      const float* src = Wraw + (size_t)(nb * 64 + fr * 16 + (l & 15)) * cH + kb * 32 + (l >> 4) * 8;
      *(short8*)(wpan + (size_t)f * 512 + l * 8) = ldfragW(src);
    }
  }
  __syncthreads();
  int wave = tid >> 6, lane = tid & 63;
  int lr = lane & 15, kg = lane >> 4;
  for (int m0 = mStart; m0 < mEnd; m0 += 512) {
    int mi = m0 + wave * 64;
    int mfg[4];
#pragma unroll
    for (int mf = 0; mf < 4; mf++) {
      int g = (mi >> 4) + mf;
      if (g > 259) g = 259;
      mfg[mf] = g - fragBase;
    }
    floatx4 acc[4][4];
#pragma unroll
    for (int mf = 0; mf < 4; mf++)
#pragma unroll
      for (int fr = 0; fr < 4; fr++) acc[mf][fr] = (floatx4){0.f, 0.f, 0.f, 0.f};
#pragma unroll 2
    for (int ks = 0; ks < 32; ks++) {
      short8 bv[4];
#pragma unroll
      for (int fr = 0; fr < 4; fr++)
        bv[fr] = *(const short8*)(wpan + ((size_t)(fr * 32 + ks) * 512) + lane * 8);
#pragma unroll
      for (int mf = 0; mf < 4; mf++) {
        short8 av = *(const short8*)(Af + ((size_t)mfg[mf] * 32 + ks) * 512 + lane * 8);
#pragma unroll
        for (int fr = 0; fr < 4; fr++)
          acc[mf][fr] = __builtin_amdgcn_mfma_f32_16x16x32_bf16(av, bv[fr], acc[mf][fr], 0, 0, 0);
      }
    }
#pragma unroll
    for (int mf = 0; mf < 4; mf++) {
#pragma unroll
      for (int fr = 0; fr < 4; fr++) {
        int n = nb * 64 + fr * 16 + lr;
        float bb = bias[n];
#pragma unroll
        for (int jj = 0; jj < 4; jj++) {
          int m = mi + mf * 16 + kg * 4 + jj;
          if (m >= storeLo && m < storeHi && !(m >= skipLo && m < skipHi))
            outp[(size_t)m * cV + n] = acc[mf][fr][jj] + bb;
        }
      }
    }
  }
}

// ---- row log-softmax, 2-pass online ----
__global__ __launch_bounds__(256) void k_lsm(float* __restrict__ outp) {
  __shared__ float wm_[4], ws_[4];
  __shared__ float blz;
  int m = blockIdx.x;
  int tid = threadIdx.x, lane = tid & 63, wid = tid >> 6;
  float4* rp4 = (float4*)(outp + (size_t)m * cV);
  float mx = -INFINITY, sm = 0.f;
  for (int n = tid; n < cV / 4; n += 256) {
    float4 v = rp4[n];
    float lm = fmaxf(fmaxf(v.x, v.y), fmaxf(v.z, v.w));
    float nm = fmaxf(mx, lm);
    sm = sm * expf(mx - nm) + expf(v.x - nm) + expf(v.y - nm) + expf(v.z - nm) + expf(v.w - nm);
    mx = nm;
  }
#pragma unroll
  for (int off = 32; off >= 1; off >>= 1) {
    float om = __shfl_xor(mx, off), os = __shfl_xor(sm, off);
    float nm = fmaxf(mx, om);
    sm = sm * expf(mx - nm) + os * expf(om - nm);
    mx = nm;
  }
  if (lane == 0) { wm_[wid] = mx; ws_[wid] = sm; }
  __syncthreads();
  if (tid == 0) {
    float M = fmaxf(fmaxf(wm_[0], wm_[1]), fmaxf(wm_[2], wm_[3]));
    float S = ws_[0] * expf(wm_[0] - M) + ws_[1] * expf(wm_[1] - M) +
              ws_[2] * expf(wm_[2] - M) + ws_[3] * expf(wm_[3] - M);
    blz = M + logf(S);
  }
  __syncthreads();
  float lz = blz;
  for (int n = tid; n < cV / 4; n += 256) {
    float4 v = rp4[n];
    v.x -= lz; v.y -= lz; v.z -= lz; v.w -= lz;
    rp4[n] = v;
  }
}

extern "C" void kernel_launch(void* const* d_in, const int* in_sizes, int n_in,
                              void* d_out, int out_size, void* d_ws, size_t ws_size,
                              hipStream_t stream) {
  (void)in_sizes; (void)n_in; (void)out_size; (void)ws_size;
  const int* enc_input  = (const int*)d_in[0];
  const int* dec_input  = (const int*)d_in[1];
  const int* length     = (const int*)d_in[2];
  const float* eps      = (const float*)d_in[3];
  const float* enc_emb  = (const float*)d_in[4];
  const float* enc_Wih  = (const float*)d_in[5];
  const float* enc_Whh  = (const float*)d_in[6];
  const float* enc_bih  = (const float*)d_in[7];
  const float* enc_bhh  = (const float*)d_in[8];
  const float* latent_W = (const float*)d_in[9];
  const float* latent_b = (const float*)d_in[10];
  const float* dec_emb  = (const float*)d_in[11];
  const float* attn_W   = (const float*)d_in[12];
  const float* attn_b   = (const float*)d_in[13];
  const float* comb_W   = (const float*)d_in[14];
  const float* comb_b   = (const float*)d_in[15];
  const float* dec_Wih  = (const float*)d_in[16];
  const float* dec_Whh  = (const float*)d_in[17];
  const float* dec_bih  = (const float*)d_in[18];
  const float* dec_bhh  = (const float*)d_in[19];
  const float* pri_W    = (const float*)d_in[20];
  const float* pri_b    = (const float*)d_in[21];
  const float* inf_W    = (const float*)d_in[22];
  const float* inf_b    = (const float*)d_in[23];
  const float* aux_W    = (const float*)d_in[24];
  const float* aux_b    = (const float*)d_in[25];
  const float* out_W    = (const float*)d_in[26];
  const float* out_b    = (const float*)d_in[27];
  float* outp = (float*)d_out;
  float* outF = outp;

  // ---- scratch layout in logp head (dead before k_logit5) ----
  size_t off = 0;
  float* c_enc = outF + off; off += 65536;
  float* c_dec = outF + off; off += 65536;
  float* scal  = outF + off; off += 4;
  off += 60;
  u16* HencZ = (u16*)(outF + off); off += 32768;
  u16* Hh    = (u16*)(outF + off); off += 66 * 32768;
  size_t zeroSpan = 196672;
  u16* encO  = (u16*)(outF + off); off += 2097152;
  u16* Xenc  = (u16*)(outF + off); off += 1048576;
  u16* Xdec  = (u16*)(outF + off); off += 1064960;
  u16* zbuf  = (u16*)(outF + off); off += 4096;
  float* mulv  = outF + off; off += 16384;
  float* biasE = outF + off; off += 4096;
  float* biasD = outF + off; off += 4096;
  float* tmp1  = outF + off; off += 1024;
  float* u0    = outF + off; off += 1024;
  float* WcxT  = outF + off; off += 524288;
  float* WczT  = outF + off; off += 131072;
  float* wPmT  = outF + off; off += 131072;
  float* auxWT = outF + off; off += 131072;
  float* M1    = outF + off; off += 131072;
  float* WfT   = outF + off; off += 1048576;
  u16* WhhEp = (u16*)(outF + off); off += 2097152;
  u16* Wbig  = (u16*)(outF + off); off += 2097152;
  u16* C1    = (u16*)(outF + off); off += 1048576;
  u16* C2    = (u16*)(outF + off); off += 262144;
  u16* Genc  = (u16*)(outF + off); off += 8388608;
  u16* Gdec  = (u16*)(outF + off); off += 8519680;
  float* priH = outF + off; off += 1064960;
  float* infH = outF + off; off += 1064960;
  float* S    = outF + off; off += 266240;
  u16* ctxH  = (u16*)(outF + off); off += 2129920;
  u16* auxH  = (u16*)(outF + off); off += 2129920;  // ends ~37.7M < 38.4M
  u16* Wf   = (u16*)(outF + WBOUT_OFF);   // frag bf16 out_W: logp rows [1200,1712)
  u16* Amat = (u16*)(outF + AMAT_OFF);    // frag bf16 A: logp tail
  u16* wsA = (u16*)d_ws;

  // ---- prep ----
  k_cvtW<<<16000, 256, 0, stream>>>(out_W, Wf);
  k_tr<<<dim3(16, 32), 256, 0, stream>>>(comb_W, 1792, 1024, WcxT);
  k_tr<<<dim3(4, 32), 256, 0, stream>>>(comb_W + 1664, 1792, 1024, WczT);
  k_tr<<<dim3(32, 4), 256, 0, stream>>>(pri_W, 1024, 128, wPmT);
  k_tr<<<dim3(4, 32), 256, 0, stream>>>(aux_W, 128, 1024, auxWT);
  k_gemv<<<4, 256, 0, stream>>>(aux_W, 128, pri_b, aux_b, tmp1, 128, 0);
  k_gemv<<<4, 256, 0, stream>>>(comb_W + 512, 1792, tmp1, comb_b, u0, 1024, 0);
  k_gemv<<<4, 256, 0, stream>>>(comb_W + 1536, 1792, pri_b, nullptr, u0, 128, 1);
  k_biasE<<<16, 256, 0, stream>>>(enc_bih, enc_bhh, biasE);
  k_biasD<<<16, 256, 0, stream>>>(dec_bih, dec_bhh, dec_Wih, u0, biasD);
  k_permW<<<4096, 256, 0, stream>>>(enc_Whh, WhhEp);
  k_gather<<<cT * cB, 256, 0, stream>>>(enc_input, enc_emb, Xenc, cT);
  k_gather<<<cTP1 * cB, 256, 0, stream>>>(dec_input, dec_emb, Xdec, cTP1);
  k_zero<<<(int)((zeroSpan + 255) / 256), 256, 0, stream>>>(c_enc, (int)zeroSpan);

  // ---- weight composition ----
  k_gemm<float, float, float, 0, 0, false><<<dim3(8, 16), 64, 0, stream>>>(
      comb_W + 512, 1792, auxWT, 1024, nullptr, comb_W + 1536, 1792, M1, 128, 1024);
  k_gemm<float, float, float, 0, 0, false><<<dim3(64, 16), 64, 0, stream>>>(
      wPmT, 128, M1, 128, nullptr, nullptr, 0, WfT, 1024, 128);
  k_gemm<float, float, u16, 1, 0, false><<<dim3(64, 64), 64, 0, stream>>>(
      dec_Wih, 1024, WfT, 1024, nullptr, dec_Whh, 1024, Wbig, 1024, 1024);
  k_gemm<float, float, u16, 1, 0, false><<<dim3(32, 64), 64, 0, stream>>>(
      dec_Wih, 1024, WcxT, 1024, nullptr, nullptr, 0, C1, 512, 1024);
  k_gemm<float, float, u16, 1, 0, false><<<dim3(8, 64), 64, 0, stream>>>(
      dec_Wih, 1024, WczT, 1024, nullptr, nullptr, 0, C2, 128, 1024);
  k_gemm<u16, float, u16, 0, 1, false><<<dim3(256, 64), 64, 0, stream>>>(
      Xenc, 512, enc_Wih, 512, biasE, nullptr, 0, Genc, 4096, 512);

  // ---- encoder loop ----
  for (int t = 0; t < cT; t++) {
    const u16* Hcur = t ? (encO + (size_t)(t - 1) * cH) : HencZ;
    int sH = t ? (cT * cH) : cH;
    k_cell2<<<256, 64, 0, stream>>>(Genc + (size_t)t * cB * 4096, Hcur, sH, WhhEp,
                                    c_enc, encO + (size_t)t * cH, cT * cH, nullptr, 0);
  }
  k_latent<<<cB, 256, 0, stream>>>(encO, c_enc, latent_W, latent_b, mulv, outp);
  k_z<<<(cB * cZ + 255) / 256, 256, 0, stream>>>(mulv, eps, zbuf);

  // ---- Gdec ----
  k_gemm<u16, u16, u16, 0, 0, false><<<dim3(256, 65), 64, 0, stream>>>(
      Xdec, 512, C1, 512, biasD, nullptr, 0, Gdec, 4096, 512);
  k_gemm<u16, u16, u16, 2, 0, true><<<dim3(256, 65), 64, 0, stream>>>(
      zbuf, 128, C2, 128, nullptr, nullptr, 0, Gdec, 4096, 128);

  // ---- decoder loop ----
  for (int t = 0; t < cTP1; t++) {
    k_cell2<<<256, 64, 0, stream>>>(Gdec + (size_t)t * cB * 4096,
                                    Hh + (size_t)t * cB * cH, cH, Wbig, c_dec,
                                    Hh + (size_t)(t + 1) * cB * cH, cH,
                                    Amat, t);
  }

  // ---- post-hoc batched math ----
  k_gemm<u16, float, float, 0, 0, false><<<dim3(16, 65), 64, 0, stream>>>(
      Hh, 1024, pri_W, 1024, pri_b, nullptr, 0, priH, 256, 1024);
  k_gemm<u16, float, float, 0, 0, false><<<dim3(4, 65), 64, 0, stream>>>(
      Xdec, 512, attn_W, 1536, attn_b, nullptr, 0, S, 64, 512);
  k_gemm<u16, float, float, 0, 0, true><<<dim3(4, 65), 64, 0, stream>>>(
      Hh, 1024, attn_W + 512, 1536, nullptr, nullptr, 0, S, 64, 1024);
  k_sctx<<<cTP1 * cB, 256, 0, stream>>>(S, enc_input, encO, ctxH);
  k_gemm<u16, float, float, 0, 0, false><<<dim3(16, 65), 64, 0, stream>>>(
      Hh, 1024, inf_W, 2048, inf_b, nullptr, 0, infH, 256, 1024);
  k_gemm<u16, float, float, 0, 0, true><<<dim3(16, 65), 64, 0, stream>>>(
      ctxH, 1024, inf_W + 1024, 2048, nullptr, nullptr, 0, infH, 256, 1024);
  k_gemm<float, float, u16, 0, 0, false><<<dim3(64, 65), 64, 0, stream>>>(
      priH, 256, aux_W, 128, aux_b, nullptr, 0, auxH, 1024, 128);
  k_scal_all<<<cTP1 * cB, 256, 0, stream>>>(priH, infH, ctxH, auxH, length, scal);
  k_scal<<<1, 64, 0, stream>>>(scal, outp);

  // ---- output projection + log-softmax ----
  k_cpyA<<<32, 256, 0, stream>>>(Amat, wsA);
  // L1: all rows, store m<4093 minus the Wf stripe; frag A + frag W panel (staged once)
  k_logit5<true><<<500, 512, 0, stream>>>(Amat, 0, Wf, nullptr, out_b, outp,
                                          0, 4096, 0, 4093, SKIP_LO, SKIP_HI);
  // L2a: the stripe rows, W streamed from f32 original
  k_logit5<false><<<500, 512, 0, stream>>>(Amat, 0, nullptr, out_W, out_b, outp,
                                           SKIP_LO, SKIP_HI, SKIP_LO, SKIP_HI, 0, 0);
  // L2b: tail rows from the d_ws frag copy
  k_logit5<false><<<500, 512, 0, stream>>>(wsA, 252, nullptr, out_W, out_b, outp,
                                           4032, 4160, 4093, 4160, 0, 0);
  k_lsm<<<cB * cTP1, 256, 0, stream>>>(outp);
}

// Round 15
// 3854.934 us; speedup vs baseline: 1.9762x; 1.0309x over previous
//
#include <hip/hip_runtime.h>
#include <hip/hip_bf16.h>
#include <cmath>

typedef unsigned short u16;
typedef __attribute__((ext_vector_type(8))) short short8;
typedef __attribute__((ext_vector_type(4))) float floatx4;

#define DEVI __device__ __forceinline__

constexpr int cV = 32000, cE = 512, cT = 64, cH = 1024, cZ = 128, cB = 64, cPAD = 31999, cTP1 = 65;
constexpr long long LOGP_SZ = 133120000LL;   // B*(T+1)*V f32 elems
constexpr long long AMAT_OFF = 130990080LL;  // logp tail: 260 frag-rows x 32 x 512 u16
constexpr long long WBOUT_OFF = 38400000LL;  // logp rows [1200,1712): frag bf16 out_W
constexpr long long PACK_OFF = 55000000LL;   // packed-B buffers (after Wf end 54.78M)
constexpr int SKIP_LO = 1200, SKIP_HI = 1712;

DEVI float b2f(u16 u) { return __uint_as_float(((unsigned)u) << 16); }
DEVI u16 f2b(float f) {
  unsigned u = __float_as_uint(f);
  unsigned r = u + 0x7FFFu + ((u >> 16) & 1u);
  return (u16)(r >> 16);
}
DEVI unsigned pk2(float lo, float hi) {
  __hip_bfloat162 t = __float22bfloat162_rn(make_float2(lo, hi));
  return *reinterpret_cast<unsigned*>(&t);
}
DEVI float sigm(float x) { return 1.f / (1.f + expf(-x)); }

DEVI short8 ldfragW(const float* __restrict__ p) {
  float4 x = *(const float4*)p, y = *(const float4*)(p + 4);
  union { unsigned u[4]; short8 s; } r;
  r.u[0] = pk2(x.x, x.y); r.u[1] = pk2(x.z, x.w);
  r.u[2] = pk2(y.x, y.y); r.u[3] = pk2(y.z, y.w);
  return r.s;
}

template <typename T>
DEVI short8 ldfrag(const T* __restrict__ p) {
  if constexpr (sizeof(T) == 2) return *(const short8*)(p);
  else return ldfragW((const float*)p);
}

template <int MAP>
DEVI int rmap(int r) {
  if constexpr (MAP == 1) return ((r & 3) << 10) | (r >> 2);
  else if constexpr (MAP == 2) return r & 63;
  else return r;
}

DEVI float dot_wf(const float* __restrict__ w, const float* __restrict__ s, int K) {
  float a0 = 0.f, a1 = 0.f, a2 = 0.f, a3 = 0.f;
#pragma unroll 4
  for (int k = 0; k < K; k += 8) {
    float4 p = *(const float4*)(w + k);
    float4 q = *(const float4*)(w + k + 4);
    a0 = fmaf(s[k + 0], p.x, a0); a1 = fmaf(s[k + 1], p.y, a1);
    a2 = fmaf(s[k + 2], p.z, a2); a3 = fmaf(s[k + 3], p.w, a3);
    a0 = fmaf(s[k + 4], q.x, a0); a1 = fmaf(s[k + 5], q.y, a1);
    a2 = fmaf(s[k + 6], q.z, a2); a3 = fmaf(s[k + 7], q.w, a3);
  }
  return (a0 + a1) + (a2 + a3);
}

__global__ __launch_bounds__(256) void k_zero(float* p, int n) {
  int i = blockIdx.x * 256 + threadIdx.x;
  if (i < n) p[i] = 0.f;
}

// ---------- generic MFMA GEMM: C[M,N] (+bias +D +C) = A[M,K] x B[N,K]^T ----------
// BFRAG: B is frag-linear bf16 (bKB = K/32 runtime).
template <typename AT, typename BT, typename CT, int AMAP, int BMAP, bool ADDC,
          bool BFRAG = false>
__global__ __launch_bounds__(64) void k_gemm(
    const AT* __restrict__ A, int lda, const BT* __restrict__ B, int ldb,
    const float* __restrict__ bias, const float* __restrict__ Dm, int ldd,
    CT* __restrict__ C, int ldc, int K, int bKB) {
  int nblk = blockIdx.x, mblk = blockIdx.y;
  int lane = threadIdx.x;
  int lr = lane & 15, kg = lane >> 4;
  const BT* Bp = B + (size_t)rmap<BMAP>(nblk * 16 + lr) * ldb + kg * 8;
  const AT* Ap[4];
#pragma unroll
  for (int mf = 0; mf < 4; mf++)
    Ap[mf] = A + (size_t)rmap<AMAP>(mblk * 64 + mf * 16 + lr) * lda + kg * 8;
  floatx4 acc[4];
#pragma unroll
  for (int mf = 0; mf < 4; mf++) acc[mf] = (floatx4){0.f, 0.f, 0.f, 0.f};
#pragma unroll 4
  for (int ks = 0; ks < K / 32; ks++) {
    short8 bv;
    if constexpr (BFRAG)
      bv = *(const short8*)((const u16*)B + ((size_t)nblk * bKB + ks) * 512 + lane * 8);
    else
      bv = ldfrag(Bp + ks * 32);
#pragma unroll
    for (int mf = 0; mf < 4; mf++) {
      short8 av = ldfrag(Ap[mf] + ks * 32);
      acc[mf] = __builtin_amdgcn_mfma_f32_16x16x32_bf16(av, bv, acc[mf], 0, 0, 0);
    }
  }
  int n = nblk * 16 + lr;
  float bs = bias ? bias[n] : 0.f;
#pragma unroll
  for (int mf = 0; mf < 4; mf++) {
#pragma unroll
    for (int jj = 0; jj < 4; jj++) {
      int m = mblk * 64 + mf * 16 + kg * 4 + jj;
      size_t ci = (size_t)m * ldc + n;
      float v = acc[mf][jj] + bs;
      if (Dm) v += Dm[(size_t)rmap<AMAP>(m) * ldd + n];
      if constexpr (ADDC) {
        if constexpr (sizeof(CT) == 2) v += b2f(C[ci]);
        else v += C[ci];
      }
      if constexpr (sizeof(CT) == 2) C[ci] = f2b(v);
      else C[ci] = v;
    }
  }
}

// ---------- serial step: gates = G[t] + Wbig x h; LSTM cell; frag-scatter h ----------
__global__ __launch_bounds__(64) void k_cell2(
    const u16* __restrict__ G, const u16* __restrict__ H, int strideH,
    const u16* __restrict__ Wb, float* __restrict__ c,
    u16* __restrict__ out1, int s1, u16* __restrict__ Afrag, int t) {
  int nb = blockIdx.x;
  int lane = threadIdx.x;
  int lr = lane & 15, kg = lane >> 4;
  const u16* Bp = Wb + (size_t)(nb * 16 + lr) * cH + kg * 8;
  floatx4 acc[4];
#pragma unroll
  for (int mf = 0; mf < 4; mf++) acc[mf] = (floatx4){0.f, 0.f, 0.f, 0.f};
#pragma unroll 8
  for (int ks = 0; ks < 32; ks++) {
    short8 bv = *(const short8*)(Bp + ks * 32);
#pragma unroll
    for (int mf = 0; mf < 4; mf++) {
      short8 av = *(const short8*)(H + (size_t)(mf * 16 + lr) * strideH + ks * 32 + kg * 8);
      acc[mf] = __builtin_amdgcn_mfma_f32_16x16x32_bf16(av, bv, acc[mf], 0, 0, 0);
    }
  }
  __shared__ float lds[16][65];
#pragma unroll
  for (int mf = 0; mf < 4; mf++)
#pragma unroll
    for (int jj = 0; jj < 4; jj++)
      lds[lr][mf * 16 + kg * 4 + jj] = acc[mf][jj];
  __syncthreads();
#pragma unroll
  for (int a = 0; a < 4; a++) {
    int b = lane;
    int j = nb * 4 + a;
    ushort4 gv = *(const ushort4*)(G + (size_t)b * 4096 + nb * 16 + 4 * a);
    float gi = lds[4 * a + 0][b] + b2f(gv.x);
    float gf = lds[4 * a + 1][b] + b2f(gv.y);
    float gg = lds[4 * a + 2][b] + b2f(gv.z);
    float go = lds[4 * a + 3][b] + b2f(gv.w);
    int ci = b * cH + j;
    float cc = c[ci];
    cc = sigm(gf) * cc + sigm(gi) * tanhf(gg);
    float hh = sigm(go) * tanhf(cc);
    c[ci] = cc;
    u16 hb = f2b(hh);
    out1[(size_t)b * s1 + j] = hb;
    if (Afrag) {
      int m = b * cTP1 + t;
      size_t idx = ((size_t)(m >> 4) * 32 + (j >> 5)) * 512 +
                   ((((j >> 3) & 3) * 16) + (m & 15)) * 8 + (j & 7);
      Afrag[idx] = hb;
    }
  }
}

// ---------- pack kernels ----------
// f32 [N(perm?)][ld] cols [col0,col0+K) -> frag-linear bf16
__global__ __launch_bounds__(256) void k_packF(const float* __restrict__ W, int ld,
                                               int col0, u16* __restrict__ Wf,
                                               int K, int perm) {
  int g = blockIdx.x * 4 + (threadIdx.x >> 6);
  int l = threadIdx.x & 63;
  int KB = K >> 5;
  int nblk = g / KB, kb = g % KB;
  int np = nblk * 16 + (l & 15);
  int src = perm ? (((np & 3) << 10) | (np >> 2)) : np;
  const float* s = W + (size_t)src * ld + col0 + kb * 32 + (l >> 4) * 8;
  *(short8*)(Wf + (size_t)g * 512 + l * 8) = ldfragW(s);
}

// bf16 [N][ld] -> frag-linear bf16
__global__ __launch_bounds__(256) void k_packB(const u16* __restrict__ W, int ld,
                                               u16* __restrict__ Wf, int K) {
  int g = blockIdx.x * 4 + (threadIdx.x >> 6);
  int l = threadIdx.x & 63;
  int KB = K >> 5;
  int nblk = g / KB, kb = g % KB;
  const u16* s = W + (size_t)(nblk * 16 + (l & 15)) * ld + kb * 32 + (l >> 4) * 8;
  *(short8*)(Wf + (size_t)g * 512 + l * 8) = *(const short8*)s;
}

// ---------- small prep kernels ----------
__global__ __launch_bounds__(256) void k_tr(const float* __restrict__ src, int ld,
                                            int R, float* __restrict__ dst) {
  __shared__ float tile[32][33];
  int c0 = blockIdx.x * 32, r0 = blockIdx.y * 32;
  int tx = threadIdx.x & 31, ty = threadIdx.x >> 5;
  for (int i = ty; i < 32; i += 8) tile[i][tx] = src[(size_t)(r0 + i) * ld + c0 + tx];
  __syncthreads();
  for (int i = ty; i < 32; i += 8) dst[(size_t)(c0 + i) * R + r0 + tx] = tile[tx][i];
}

__global__ __launch_bounds__(256) void k_gemv(const float* __restrict__ W, int ld,
                                              const float* __restrict__ x,
                                              const float* __restrict__ b,
                                              float* __restrict__ out, int K, int add) {
  int n = blockIdx.x * 256 + threadIdx.x;
  const float* w = W + (size_t)n * ld;
  float s = b ? b[n] : 0.f;
  for (int k = 0; k < K; k += 4) {
    float4 wv = *(const float4*)(w + k);
    float4 xv = *(const float4*)(x + k);
    s += wv.x * xv.x + wv.y * xv.y + wv.z * xv.z + wv.w * xv.w;
  }
  if (add) out[n] += s; else out[n] = s;
}

__global__ __launch_bounds__(256) void k_biasD(const float* __restrict__ bih,
                                               const float* __restrict__ bhh,
                                               const float* __restrict__ Wih,
                                               const float* __restrict__ u0,
                                               float* __restrict__ biasD) {
  int np = blockIdx.x * 256 + threadIdx.x;
  int src = ((np & 3) << 10) | (np >> 2);
  const float* w = Wih + (size_t)src * cH;
  float s = bih[src] + bhh[src];
  for (int k = 0; k < cH; k += 4) {
    float4 wv = *(const float4*)(w + k);
    float4 xv = *(const float4*)(u0 + k);
    s += wv.x * xv.x + wv.y * xv.y + wv.z * xv.z + wv.w * xv.w;
  }
  biasD[np] = s;
}

__global__ __launch_bounds__(256) void k_biasE(const float* __restrict__ bih,
                                               const float* __restrict__ bhh,
                                               float* __restrict__ biasE) {
  int np = blockIdx.x * 256 + threadIdx.x;
  int src = ((np & 3) << 10) | (np >> 2);
  biasE[np] = bih[src] + bhh[src];
}

__global__ __launch_bounds__(256) void k_permW(const float* __restrict__ Whh,
                                               u16* __restrict__ Wp) {
  int np = blockIdx.x;
  int src = ((np & 3) << 10) | (np >> 2);
  const float* w = Whh + (size_t)src * cH;
  u16* d = Wp + (size_t)np * cH;
  int tid = threadIdx.x;
#pragma unroll
  for (int p = 0; p < 4; p++) d[tid + p * 256] = f2b(w[tid + p * 256]);
}

// out_W (f32 row-major) -> frag-linear bf16: one wave per 16x32 frag
__global__ __launch_bounds__(256) void k_cvtW(const float* __restrict__ W,
                                              u16* __restrict__ Wf) {
  int g = blockIdx.x * 4 + (threadIdx.x >> 6);
  int l = threadIdx.x & 63;
  int nblk = g >> 5, kb = g & 31;
  const float* src = W + (size_t)(nblk * 16 + (l & 15)) * cH + kb * 32 + (l >> 4) * 8;
  *(short8*)(Wf + (size_t)g * 512 + l * 8) = ldfragW(src);
}

__global__ __launch_bounds__(256) void k_gather(const int* __restrict__ tok,
                                                const float* __restrict__ emb,
                                                u16* __restrict__ dst, int Tlen) {
  int r = blockIdx.x;
  int t = r >> 6, b = r & 63;
  const float* src = emb + (size_t)tok[b * Tlen + t] * cE;
  u16* d = dst + (size_t)r * cE;
  int tid = threadIdx.x;
  for (int k = tid; k < cE; k += 256) d[k] = f2b(src[k]);
}

// ---------- latent / z ----------
__global__ __launch_bounds__(256) void k_latent(
    const u16* __restrict__ encO, const float* __restrict__ cT2,
    const float* __restrict__ W, const float* __restrict__ bias,
    float* __restrict__ mulv, float* __restrict__ outp) {
  __shared__ float s[2 * cH];
  int b = blockIdx.x;
  int n = threadIdx.x;
  for (int k = n; k < cH; k += 256) {
    s[k] = b2f(encO[((size_t)b * cT + 63) * cH + k]);
    s[cH + k] = cT2[b * cH + k];
  }
  __syncthreads();
  float acc = bias[n] + dot_wf(W + (size_t)n * (2 * cH), s, 2 * cH);
  mulv[b * 256 + n] = acc;
  if (n < cZ)
    outp[LOGP_SZ + (size_t)b * cZ + n] = acc;
  else
    outp[LOGP_SZ + (size_t)cB * cZ + (size_t)b * cZ + (n - cZ)] = acc;
}

__global__ __launch_bounds__(256) void k_z(const float* __restrict__ mulv,
                                           const float* __restrict__ eps,
                                           u16* __restrict__ zbuf) {
  int i = blockIdx.x * 256 + threadIdx.x;
  if (i >= cB * cZ) return;
  int b = i >> 7, zi = i & 127;
  float mu = mulv[b * 256 + zi], lv = mulv[b * 256 + cZ + zi];
  zbuf[i] = f2b(mu + expf(0.5f * lv) * eps[i]);
}

// ---------- post-hoc: softmax + ctx ----------
__global__ __launch_bounds__(256) void k_sctx(
    const float* __restrict__ S, const int* __restrict__ enc_input,
    const u16* __restrict__ encO, u16* __restrict__ ctxH) {
  __shared__ float wat[cT];
  int tb = blockIdx.x;
  int b = tb & 63;
  int tid = threadIdx.x;
  if (tid < cT) {
    float sc = S[(size_t)tb * cT + tid];
    if (enc_input[b * cT + tid] == cPAD) sc = -INFINITY;
    float m = sc;
#pragma unroll
    for (int off = 32; off >= 1; off >>= 1) m = fmaxf(m, __shfl_xor(m, off));
    float p = expf(sc - m);
    float ssum = p;
#pragma unroll
    for (int off = 32; off >= 1; off >>= 1) ssum += __shfl_xor(ssum, off);
    wat[tid] = p / ssum;
  }
  __syncthreads();
#pragma unroll
  for (int p = 0; p < 4; p++) {
    int j = tid + p * 256;
    float s = 0.f;
    const u16* e = encO + ((size_t)b * cT) * cH + j;
#pragma unroll 8
    for (int t2 = 0; t2 < cT; t2++) s += wat[t2] * b2f(e[(size_t)t2 * cH]);
    ctxH[(size_t)tb * cH + j] = f2b(s);
  }
}

// ---------- post-hoc: kld + aux_c reductions ----------
__global__ __launch_bounds__(256) void k_scal_all(
    const float* __restrict__ priH, const float* __restrict__ infH,
    const u16* __restrict__ ctxH, const u16* __restrict__ auxH,
    const int* __restrict__ length, float* __restrict__ scal) {
  __shared__ float red[256];
  int tb = blockIdx.x;
  int t = tb >> 6, b = tb & 63;
  int tid = threadIdx.x;
  float r = 0.f;
  if (tid < cZ) {
    float pm = priH[(size_t)tb * 256 + tid], plv = priH[(size_t)tb * 256 + cZ + tid];
    float im = infH[(size_t)tb * 256 + tid], ilv = infH[(size_t)tb * 256 + cZ + tid];
    float d = im - pm;
    r = plv - ilv + expf(ilv - plv) + d * d * expf(-plv) - 1.f;
  }
  red[tid] = r;
  __syncthreads();
  for (int sft = 128; sft > 0; sft >>= 1) {
    if (tid < sft) red[tid] += red[tid + sft];
    __syncthreads();
  }
  if (tid == 0 && (length[b] + 1 > t)) atomicAdd(&scal[0], 0.5f * red[0]);
  __syncthreads();
  float r2 = 0.f;
#pragma unroll
  for (int p = 0; p < 4; p++) {
    int j = tid + p * 256;
    float d = b2f(ctxH[(size_t)tb * cH + j]) - b2f(auxH[(size_t)tb * cH + j]);
    r2 += d * d;
  }
  red[tid] = r2;
  __syncthreads();
  for (int sft = 128; sft > 0; sft >>= 1) {
    if (tid < sft) red[tid] += red[tid + sft];
    __syncthreads();
  }
  if (tid == 0) atomicAdd(&scal[1], red[0]);
}

__global__ void k_scal(const float* __restrict__ scal, float* __restrict__ outp) {
  if (threadIdx.x == 0) {
    outp[LOGP_SZ + 2 * cB * cZ] = scal[0];
    outp[LOGP_SZ + 2 * cB * cZ + 1] = scal[1];
  }
}

// copy Amat frag m-blocks [252,260) (256 KB) into d_ws
__global__ __launch_bounds__(256) void k_cpyA(const u16* __restrict__ src,
                                              u16* __restrict__ dst) {
  int i = blockIdx.x * 256 + threadIdx.x;
  ((uint4*)dst)[i] = ((const uint4*)(src + (size_t)252 * 32 * 512))[i];
}

// ---- output projection v5: N_BLK=64, FULL 128KB W panel staged ONCE, frag A ----
template <bool WFRAG>
__global__ __launch_bounds__(512) void k_logit5(
    const u16* __restrict__ Af, int fragBase,
    const u16* __restrict__ Wf, const float* __restrict__ Wraw,
    const float* __restrict__ bias, float* __restrict__ outp,
    int mStart, int mEnd, int storeLo, int storeHi, int skipLo, int skipHi) {
  __shared__ u16 wpan[65536];
  int nb = blockIdx.x;
  int tid = threadIdx.x;
  if constexpr (WFRAG) {
    const uint4* src = (const uint4*)(Wf + (size_t)nb * 65536);
    uint4* dst = (uint4*)wpan;
#pragma unroll
    for (int q = 0; q < 16; q++) dst[tid + q * 512] = src[tid + q * 512];
  } else {
    int wv = tid >> 6, l = tid & 63;
    for (int f = wv; f < 128; f += 8) {
      int fr = f >> 5, kb = f & 31;
      const float* src = Wraw + (size_t)(nb * 64 + fr * 16 + (l & 15)) * cH + kb * 32 + (l >> 4) * 8;
      *(short8*)(wpan + (size_t)f * 512 + l * 8) = ldfragW(src);
    }
  }
  __syncthreads();
  int wave = tid >> 6, lane = tid & 63;
  int lr = lane & 15, kg = lane >> 4;
  for (int m0 = mStart; m0 < mEnd; m0 += 512) {
    int mi = m0 + wave * 64;
    int mfg[4];
#pragma unroll
    for (int mf = 0; mf < 4; mf++) {
      int g = (mi >> 4) + mf;
      if (g > 259) g = 259;
      mfg[mf] = g - fragBase;
    }
    floatx4 acc[4][4];
#pragma unroll
    for (int mf = 0; mf < 4; mf++)
#pragma unroll
      for (int fr = 0; fr < 4; fr++) acc[mf][fr] = (floatx4){0.f, 0.f, 0.f, 0.f};
#pragma unroll 2
    for (int ks = 0; ks < 32; ks++) {
      short8 bv[4];
#pragma unroll
      for (int fr = 0; fr < 4; fr++)
        bv[fr] = *(const short8*)(wpan + ((size_t)(fr * 32 + ks) * 512) + lane * 8);
#pragma unroll
      for (int mf = 0; mf < 4; mf++) {
        short8 av = *(const short8*)(Af + ((size_t)mfg[mf] * 32 + ks) * 512 + lane * 8);
#pragma unroll
        for (int fr = 0; fr < 4; fr++)
          acc[mf][fr] = __builtin_amdgcn_mfma_f32_16x16x32_bf16(av, bv[fr], acc[mf][fr], 0, 0, 0);
      }
    }
#pragma unroll
    for (int mf = 0; mf < 4; mf++) {
#pragma unroll
      for (int fr = 0; fr < 4; fr++) {
        int n = nb * 64 + fr * 16 + lr;
        float bb = bias[n];
#pragma unroll
        for (int jj = 0; jj < 4; jj++) {
          int m = mi + mf * 16 + kg * 4 + jj;
          if (m >= storeLo && m < storeHi && !(m >= skipLo && m < skipHi))
            outp[(size_t)m * cV + n] = acc[mf][fr][jj] + bb;
        }
      }
    }
  }
}

// ---- row log-softmax, 2-pass online ----
__global__ __launch_bounds__(256) void k_lsm(float* __restrict__ outp) {
  __shared__ float wm_[4], ws_[4];
  __shared__ float blz;
  int m = blockIdx.x;
  int tid = threadIdx.x, lane = tid & 63, wid = tid >> 6;
  float4* rp4 = (float4*)(outp + (size_t)m * cV);
  float mx = -INFINITY, sm = 0.f;
  for (int n = tid; n < cV / 4; n += 256) {
    float4 v = rp4[n];
    float lm = fmaxf(fmaxf(v.x, v.y), fmaxf(v.z, v.w));
    float nm = fmaxf(mx, lm);
    sm = sm * expf(mx - nm) + expf(v.x - nm) + expf(v.y - nm) + expf(v.z - nm) + expf(v.w - nm);
    mx = nm;
  }
#pragma unroll
  for (int off = 32; off >= 1; off >>= 1) {
    float om = __shfl_xor(mx, off), os = __shfl_xor(sm, off);
    float nm = fmaxf(mx, om);
    sm = sm * expf(mx - nm) + os * expf(om - nm);
    mx = nm;
  }
  if (lane == 0) { wm_[wid] = mx; ws_[wid] = sm; }
  __syncthreads();
  if (tid == 0) {
    float M = fmaxf(fmaxf(wm_[0], wm_[1]), fmaxf(wm_[2], wm_[3]));
    float S = ws_[0] * expf(wm_[0] - M) + ws_[1] * expf(wm_[1] - M) +
              ws_[2] * expf(wm_[2] - M) + ws_[3] * expf(wm_[3] - M);
    blz = M + logf(S);
  }
  __syncthreads();
  float lz = blz;
  for (int n = tid; n < cV / 4; n += 256) {
    float4 v = rp4[n];
    v.x -= lz; v.y -= lz; v.z -= lz; v.w -= lz;
    rp4[n] = v;
  }
}

extern "C" void kernel_launch(void* const* d_in, const int* in_sizes, int n_in,
                              void* d_out, int out_size, void* d_ws, size_t ws_size,
                              hipStream_t stream) {
  (void)in_sizes; (void)n_in; (void)out_size; (void)ws_size;
  const int* enc_input  = (const int*)d_in[0];
  const int* dec_input  = (const int*)d_in[1];
  const int* length     = (const int*)d_in[2];
  const float* eps      = (const float*)d_in[3];
  const float* enc_emb  = (const float*)d_in[4];
  const float* enc_Wih  = (const float*)d_in[5];
  const float* enc_Whh  = (const float*)d_in[6];
  const float* enc_bih  = (const float*)d_in[7];
  const float* enc_bhh  = (const float*)d_in[8];
  const float* latent_W = (const float*)d_in[9];
  const float* latent_b = (const float*)d_in[10];
  const float* dec_emb  = (const float*)d_in[11];
  const float* attn_W   = (const float*)d_in[12];
  const float* attn_b   = (const float*)d_in[13];
  const float* comb_W   = (const float*)d_in[14];
  const float* comb_b   = (const float*)d_in[15];
  const float* dec_Wih  = (const float*)d_in[16];
  const float* dec_Whh  = (const float*)d_in[17];
  const float* dec_bih  = (const float*)d_in[18];
  const float* dec_bhh  = (const float*)d_in[19];
  const float* pri_W    = (const float*)d_in[20];
  const float* pri_b    = (const float*)d_in[21];
  const float* inf_W    = (const float*)d_in[22];
  const float* inf_b    = (const float*)d_in[23];
  const float* aux_W    = (const float*)d_in[24];
  const float* aux_b    = (const float*)d_in[25];
  const float* out_W    = (const float*)d_in[26];
  const float* out_b    = (const float*)d_in[27];
  float* outp = (float*)d_out;
  float* outF = outp;

  // ---- scratch layout in logp head (dead before k_logit5) ----
  size_t off = 0;
  float* c_enc = outF + off; off += 65536;
  float* c_dec = outF + off; off += 65536;
  float* scal  = outF + off; off += 4;
  off += 60;
  u16* HencZ = (u16*)(outF + off); off += 32768;
  u16* Hh    = (u16*)(outF + off); off += 66 * 32768;
  size_t zeroSpan = 196672;
  u16* encO  = (u16*)(outF + off); off += 2097152;
  u16* Xenc  = (u16*)(outF + off); off += 1048576;
  u16* Xdec  = (u16*)(outF + off); off += 1064960;
  u16* zbuf  = (u16*)(outF + off); off += 4096;
  float* mulv  = outF + off; off += 16384;
  float* biasE = outF + off; off += 4096;
  float* biasD = outF + off; off += 4096;
  float* tmp1  = outF + off; off += 1024;
  float* u0    = outF + off; off += 1024;
  float* WcxT  = outF + off; off += 524288;
  float* WczT  = outF + off; off += 131072;
  float* wPmT  = outF + off; off += 131072;
  float* auxWT = outF + off; off += 131072;
  float* M1    = outF + off; off += 131072;
  float* WfT   = outF + off; off += 1048576;
  u16* WhhEp = (u16*)(outF + off); off += 2097152;
  u16* Wbig  = (u16*)(outF + off); off += 2097152;
  u16* C1    = (u16*)(outF + off); off += 1048576;
  u16* C2    = (u16*)(outF + off); off += 262144;
  u16* Genc  = (u16*)(outF + off); off += 8388608;
  u16* Gdec  = (u16*)(outF + off); off += 8519680;
  float* priH = outF + off; off += 1064960;
  float* infH = outF + off; off += 1064960;
  float* S    = outF + off; off += 266240;
  u16* ctxH  = (u16*)(outF + off); off += 2129920;
  u16* auxH  = (u16*)(outF + off); off += 2129920;  // ends ~37.7M < 38.4M
  u16* Wf   = (u16*)(outF + WBOUT_OFF);
  u16* Amat = (u16*)(outF + AMAT_OFF);
  u16* wsA = (u16*)d_ws;
  // packed-B buffers at PACK_OFF (dead before k_logit5 writes)
  size_t poff = PACK_OFF;
  u16* WihEf = (u16*)(outF + poff); poff += 1048576;   // 4096x512
  u16* C1f   = (u16*)(outF + poff); poff += 1048576;   // 4096x512
  u16* C2f   = (u16*)(outF + poff); poff += 262144;    // 4096x128
  u16* priWf = (u16*)(outF + poff); poff += 131072;    // 256x1024
  u16* attnXf= (u16*)(outF + poff); poff += 16384;     // 64x512
  u16* attnHf= (u16*)(outF + poff); poff += 32768;     // 64x1024
  u16* infWaf= (u16*)(outF + poff); poff += 131072;    // 256x1024
  u16* infWbf= (u16*)(outF + poff); poff += 131072;    // 256x1024
  u16* auxWf = (u16*)(outF + poff); poff += 65536;     // 1024x128

  // ---- prep ----
  k_cvtW<<<16000, 256, 0, stream>>>(out_W, Wf);
  k_tr<<<dim3(16, 32), 256, 0, stream>>>(comb_W, 1792, 1024, WcxT);
  k_tr<<<dim3(4, 32), 256, 0, stream>>>(comb_W + 1664, 1792, 1024, WczT);
  k_tr<<<dim3(32, 4), 256, 0, stream>>>(pri_W, 1024, 128, wPmT);
  k_tr<<<dim3(4, 32), 256, 0, stream>>>(aux_W, 128, 1024, auxWT);
  k_gemv<<<4, 256, 0, stream>>>(aux_W, 128, pri_b, aux_b, tmp1, 128, 0);
  k_gemv<<<4, 256, 0, stream>>>(comb_W + 512, 1792, tmp1, comb_b, u0, 1024, 0);
  k_gemv<<<4, 256, 0, stream>>>(comb_W + 1536, 1792, pri_b, nullptr, u0, 128, 1);
  k_biasE<<<16, 256, 0, stream>>>(enc_bih, enc_bhh, biasE);
  k_biasD<<<16, 256, 0, stream>>>(dec_bih, dec_bhh, dec_Wih, u0, biasD);
  k_permW<<<4096, 256, 0, stream>>>(enc_Whh, WhhEp);
  k_gather<<<cT * cB, 256, 0, stream>>>(enc_input, enc_emb, Xenc, cT);
  k_gather<<<cTP1 * cB, 256, 0, stream>>>(dec_input, dec_emb, Xdec, cTP1);
  k_zero<<<(int)((zeroSpan + 255) / 256), 256, 0, stream>>>(c_enc, (int)zeroSpan);
  // packed B panels (f32 sources)
  k_packF<<<1024, 256, 0, stream>>>(enc_Wih, 512, 0, WihEf, 512, 1);
  k_packF<<<128, 256, 0, stream>>>(pri_W, 1024, 0, priWf, 1024, 0);
  k_packF<<<16, 256, 0, stream>>>(attn_W, 1536, 0, attnXf, 512, 0);
  k_packF<<<32, 256, 0, stream>>>(attn_W, 1536, 512, attnHf, 1024, 0);
  k_packF<<<128, 256, 0, stream>>>(inf_W, 2048, 0, infWaf, 1024, 0);
  k_packF<<<128, 256, 0, stream>>>(inf_W, 2048, 1024, infWbf, 1024, 0);
  k_packF<<<64, 256, 0, stream>>>(aux_W, 128, 0, auxWf, 128, 0);

  // ---- weight composition ----
  k_gemm<float, float, float, 0, 0, false><<<dim3(8, 16), 64, 0, stream>>>(
      comb_W + 512, 1792, auxWT, 1024, nullptr, comb_W + 1536, 1792, M1, 128, 1024, 0);
  k_gemm<float, float, float, 0, 0, false><<<dim3(64, 16), 64, 0, stream>>>(
      wPmT, 128, M1, 128, nullptr, nullptr, 0, WfT, 1024, 128, 0);
  k_gemm<float, float, u16, 1, 0, false><<<dim3(64, 64), 64, 0, stream>>>(
      dec_Wih, 1024, WfT, 1024, nullptr, dec_Whh, 1024, Wbig, 1024, 1024, 0);
  k_gemm<float, float, u16, 1, 0, false><<<dim3(32, 64), 64, 0, stream>>>(
      dec_Wih, 1024, WcxT, 1024, nullptr, nullptr, 0, C1, 512, 1024, 0);
  k_gemm<float, float, u16, 1, 0, false><<<dim3(8, 64), 64, 0, stream>>>(
      dec_Wih, 1024, WczT, 1024, nullptr, nullptr, 0, C2, 128, 1024, 0);
  // pack composed C1/C2 (bf16) to frag
  k_packB<<<1024, 256, 0, stream>>>(C1, 512, C1f, 512);
  k_packB<<<256, 256, 0, stream>>>(C2, 128, C2f, 128);
  // Genc = Xenc x WihEf^T + biasE  (frag B)
  k_gemm<u16, u16, u16, 0, 0, false, true><<<dim3(256, 64), 64, 0, stream>>>(
      Xenc, 512, WihEf, 512, biasE, nullptr, 0, Genc, 4096, 512, 16);

  // ---- encoder loop ----
  for (int t = 0; t < cT; t++) {
    const u16* Hcur = t ? (encO + (size_t)(t - 1) * cH) : HencZ;
    int sH = t ? (cT * cH) : cH;
    k_cell2<<<256, 64, 0, stream>>>(Genc + (size_t)t * cB * 4096, Hcur, sH, WhhEp,
                                    c_enc, encO + (size_t)t * cH, cT * cH, nullptr, 0);
  }
  k_latent<<<cB, 256, 0, stream>>>(encO, c_enc, latent_W, latent_b, mulv, outp);
  k_z<<<(cB * cZ + 255) / 256, 256, 0, stream>>>(mulv, eps, zbuf);

  // ---- Gdec ----
  k_gemm<u16, u16, u16, 0, 0, false, true><<<dim3(256, 65), 64, 0, stream>>>(
      Xdec, 512, C1f, 512, biasD, nullptr, 0, Gdec, 4096, 512, 16);
  k_gemm<u16, u16, u16, 2, 0, true, true><<<dim3(256, 65), 64, 0, stream>>>(
      zbuf, 128, C2f, 128, nullptr, nullptr, 0, Gdec, 4096, 128, 4);

  // ---- decoder loop ----
  for (int t = 0; t < cTP1; t++) {
    k_cell2<<<256, 64, 0, stream>>>(Gdec + (size_t)t * cB * 4096,
                                    Hh + (size_t)t * cB * cH, cH, Wbig, c_dec,
                                    Hh + (size_t)(t + 1) * cB * cH, cH,
                                    Amat, t);
  }

  // ---- post-hoc batched math (frag B everywhere) ----
  k_gemm<u16, u16, float, 0, 0, false, true><<<dim3(16, 65), 64, 0, stream>>>(
      Hh, 1024, priWf, 1024, pri_b, nullptr, 0, priH, 256, 1024, 32);
  k_gemm<u16, u16, float, 0, 0, false, true><<<dim3(4, 65), 64, 0, stream>>>(
      Xdec, 512, attnXf, 512, attn_b, nullptr, 0, S, 64, 512, 16);
  k_gemm<u16, u16, float, 0, 0, true, true><<<dim3(4, 65), 64, 0, stream>>>(
      Hh, 1024, attnHf, 1024, nullptr, nullptr, 0, S, 64, 1024, 32);
  k_sctx<<<cTP1 * cB, 256, 0, stream>>>(S, enc_input, encO, ctxH);
  k_gemm<u16, u16, float, 0, 0, false, true><<<dim3(16, 65), 64, 0, stream>>>(
      Hh, 1024, infWaf, 1024, inf_b, nullptr, 0, infH, 256, 1024, 32);
  k_gemm<u16, u16, float, 0, 0, true, true><<<dim3(16, 65), 64, 0, stream>>>(
      ctxH, 1024, infWbf, 1024, nullptr, nullptr, 0, infH, 256, 1024, 32);
  k_gemm<float, u16, u16, 0, 0, false, true><<<dim3(64, 65), 64, 0, stream>>>(
      priH, 256, auxWf, 128, aux_b, nullptr, 0, auxH, 1024, 128, 4);
  k_scal_all<<<cTP1 * cB, 256, 0, stream>>>(priH, infH, ctxH, auxH, length, scal);
  k_scal<<<1, 64, 0, stream>>>(scal, outp);

  // ---- output projection + log-softmax ----
  k_cpyA<<<32, 256, 0, stream>>>(Amat, wsA);
  k_logit5<true><<<500, 512, 0, stream>>>(Amat, 0, Wf, nullptr, out_b, outp,
                                          0, 4096, 0, 4093, SKIP_LO, SKIP_HI);
  k_logit5<false><<<500, 512, 0, stream>>>(Amat, 0, nullptr, out_W, out_b, outp,
                                           SKIP_LO, SKIP_HI, SKIP_LO, SKIP_HI, 0, 0);
  k_logit5<false><<<500, 512, 0, stream>>>(wsA, 252, nullptr, out_W, out_b, outp,
                                           4032, 4160, 4093, 4160, 0, 0);
  k_lsm<<<cB * cTP1, 256, 0, stream>>>(outp);
}